// Round 5
// baseline (2105.751 us; speedup 1.0000x reference)
//
#include <hip/hip_runtime.h>

// SBMAttention — round 5: oracle implementation with FLOAT32 outputs.
// Root cause of rounds 1-4: outputs are f32 (reference returns float32), not
// bf16. The bf16 graph writes at half-offset landed inside the f32 X region,
// producing the constant 1.4727 artifact. All outputs now stored as f32 at
// element offsets: X [0,2097152) | sparsity [+8) | graph [67.1M) | attn [67.1M).
// Sampling chain (S, MLP, Qhat, SK, expA) in f64 to match the np reference on
// every Bernoulli decision. Attention math reference-faithful (row max, Z,
// sum-p floored by 1e-12 at reference scale).

typedef float  f32x4 __attribute__((ext_vector_type(4)));
typedef float  f32x8 __attribute__((ext_vector_type(8)));
typedef _Float16 f16;
typedef _Float16 f16x8 __attribute__((ext_vector_type(8)));

// ---------------- kS: cluster softmax (f64) ----------------
__global__ __launch_bounds__(256) void kS(const float* __restrict__ emb,
                                          double* __restrict__ wsS,
                                          float* __restrict__ wsSP) {
  __shared__ double c[16][65];
  __shared__ double red[256];
  const int t = threadIdx.x, h = blockIdx.x;
  if (t == 0) wsSP[h] = 0.f;  // zero sparsity accumulator each launch
  for (int i = t; i < 1024; i += 256) c[i >> 6][i & 63] = (double)emb[(size_t)h * 1024 + i];
  __syncthreads();
  const int k = t >> 4, j = t & 15;
  double acc = 0.0;
  for (int d = 0; d < 64; ++d) acc += c[k][d] * c[j][d];
  red[t] = acc; __syncthreads();
  for (int s = 128; s > 0; s >>= 1) { if (t < s) red[t] = fmax(red[t], red[t + s]); __syncthreads(); }
  const double mx = red[0]; __syncthreads();
  const double e = exp(acc - mx);
  red[t] = e; __syncthreads();
  for (int s = 128; s > 0; s >>= 1) { if (t < s) red[t] += red[t + s]; __syncthreads(); }
  wsS[h * 256 + t] = e / red[0];
}

// ---------------- kMLP: proj + hats (f64, sampling-critical) ----------------
__global__ __launch_bounds__(256) void kMLP(
    const float* __restrict__ Q, const float* __restrict__ K,
    const float* __restrict__ emb,
    const float* __restrict__ W1, const float* __restrict__ b1,
    const float* __restrict__ W2, const float* __restrict__ b2,
    const float* __restrict__ W3, const float* __restrict__ b3,
    const double* __restrict__ wsS,
    double* __restrict__ QHAT, double* __restrict__ SKT) {
  __shared__ double Xt[64][65];
  __shared__ float  Wl[64][65];
  __shared__ float  bsS[64];
  __shared__ float  cl[16][65];      // emb is f32: lossless as f32
  __shared__ double kh[64][17];
  __shared__ double Sl[256];

  const int t = threadIdx.x;
  const int blk = blockIdx.x;
  const int side = blk >> 9;          // 0 = Q tokens, 1 = K tokens
  const int idx = blk & 511;
  const int bh = idx >> 5;
  const int h = bh & 7;
  const int chunk = idx & 31;
  const size_t t0 = (size_t)bh * 2048 + (size_t)chunk * 64;

  const float* src = side ? K : Q;
  for (int i = t; i < 4096; i += 256) Xt[i >> 6][i & 63] = (double)src[t0 * 64 + i];

  const float* Ws[3] = {W1, W2, W3};
  const float* bs[3] = {b1, b2, b3};
  const int te = t & 15, tt = t >> 4;
  const int e0 = te * 4, tok0 = tt * 4;

  for (int l = 0; l < 3; ++l) {
    __syncthreads();
    for (int i = t; i < 4096; i += 256) Wl[i >> 6][i & 63] = Ws[l][i];
    if (t < 64) bsS[t] = bs[l][t];
    __syncthreads();
    double o[4][4];
#pragma unroll
    for (int i = 0; i < 4; ++i)
#pragma unroll
      for (int j = 0; j < 4; ++j) o[i][j] = 0.0;
    for (int d = 0; d < 64; ++d) {
      const double x0 = Xt[tok0 + 0][d], x1 = Xt[tok0 + 1][d], x2 = Xt[tok0 + 2][d], x3 = Xt[tok0 + 3][d];
      const double w0 = (double)Wl[e0 + 0][d], w1 = (double)Wl[e0 + 1][d];
      const double w2 = (double)Wl[e0 + 2][d], w3 = (double)Wl[e0 + 3][d];
      o[0][0] += x0 * w0; o[0][1] += x0 * w1; o[0][2] += x0 * w2; o[0][3] += x0 * w3;
      o[1][0] += x1 * w0; o[1][1] += x1 * w1; o[1][2] += x1 * w2; o[1][3] += x1 * w3;
      o[2][0] += x2 * w0; o[2][1] += x2 * w1; o[2][2] += x2 * w2; o[2][3] += x2 * w3;
      o[3][0] += x3 * w0; o[3][1] += x3 * w1; o[3][2] += x3 * w2; o[3][3] += x3 * w3;
    }
#pragma unroll
    for (int i = 0; i < 4; ++i)
#pragma unroll
      for (int j = 0; j < 4; ++j) {
        double v = o[i][j] + (double)bsS[e0 + j];   // bias AFTER full sum
        if (l < 2) v = fmax(v, 0.0);
        o[i][j] = v;
      }
    __syncthreads();
#pragma unroll
    for (int i = 0; i < 4; ++i)
#pragma unroll
      for (int j = 0; j < 4; ++j) Xt[tok0 + i][e0 + j] = o[i][j];
  }
  __syncthreads();
  for (int i = t; i < 1024; i += 256) cl[i >> 6][i & 63] = emb[(size_t)h * 1024 + i];
  if (side) { for (int i = t; i < 256; i += 256) Sl[i] = wsS[h * 256 + i]; }
  __syncthreads();

  const int tok = t >> 2, k0 = (t & 3) * 4;
  double z[4] = {0.0, 0.0, 0.0, 0.0};
  for (int d = 0; d < 64; ++d) {
    const double xv = Xt[tok][d];
    z[0] += xv * (double)cl[k0 + 0][d]; z[1] += xv * (double)cl[k0 + 1][d];
    z[2] += xv * (double)cl[k0 + 2][d]; z[3] += xv * (double)cl[k0 + 3][d];
  }
  double hat[4];
#pragma unroll
  for (int j = 0; j < 4; ++j) hat[j] = 1.0 / (1.0 + exp(-z[j]));

  if (!side) {
#pragma unroll
    for (int j = 0; j < 4; ++j) QHAT[(t0 + tok) * 16 + k0 + j] = hat[j];
  } else {
    kh[tok][k0 + 0] = hat[0]; kh[tok][k0 + 1] = hat[1];
    kh[tok][k0 + 2] = hat[2]; kh[tok][k0 + 3] = hat[3];
    __syncthreads();
    double sk[4] = {0.0, 0.0, 0.0, 0.0};
    for (int jj = 0; jj < 16; ++jj) {
      const double kv = kh[tok][jj];
      sk[0] += Sl[(k0 + 0) * 16 + jj] * kv; sk[1] += Sl[(k0 + 1) * 16 + jj] * kv;
      sk[2] += Sl[(k0 + 2) * 16 + jj] * kv; sk[3] += Sl[(k0 + 3) * 16 + jj] * kv;
    }
#pragma unroll
    for (int j = 0; j < 4; ++j) SKT[(t0 + tok) * 16 + k0 + j] = sk[j];
  }
}

// ---------------- kMainO: attention (f32 outputs) ----------------
#define ORO 8
__global__ __launch_bounds__(256) void kMainO(
    const float* __restrict__ Q, const int* __restrict__ maskp,
    const float* __restrict__ noise,
    const double* __restrict__ qhat, const double* __restrict__ skt,
    const float* __restrict__ Kg, const float* __restrict__ Vg,
    float* __restrict__ wsSP,
    float* __restrict__ XOUT, float* __restrict__ GOUT,
    float* __restrict__ AOUT) {
  __shared__ f16 sA[ORO][2048];          // 32 KB: s = dot/8, then attn (fp16)
  __shared__ float Ks[32][68];           // K chunk, later V chunk (padded)
  __shared__ double sktS[32][17];        // SKT chunk (f64, padded)
  __shared__ unsigned int gb[ORO][64];   // sample bits
  __shared__ float redM[ORO][33], redZ[ORO][33], redP[ORO][33];
  __shared__ float rowM[ORO], rowScale[ORO];
  __shared__ float xh[ORO][64];
  __shared__ float spRed[4];

  const int t = threadIdx.x;
  const int bh = blockIdx.y, b = bh >> 3, h = bh & 7;
  const int n0 = blockIdx.x * ORO;
  const int tn = t >> 5, tm = t & 31;

  const float* qr = Q + ((size_t)bh * 2048 + n0 + tn) * 64;
  f32x4 qv[16];
#pragma unroll
  for (int c = 0; c < 16; ++c) qv[c] = *(const f32x4*)(qr + 4 * c);
  double dqh[16];
  const double* qhp = qhat + ((size_t)bh * 2048 + n0 + tn) * 16;
#pragma unroll
  for (int k = 0; k < 16; ++k) dqh[k] = qhp[k];

  const int* mkp = maskp + b * 2048;
  const float* nrow = noise + (size_t)(bh * 2048 + n0 + tn) * 2048;
  const double* sktp = skt + (size_t)bh * 2048 * 16;
  const size_t kvbase = (size_t)bh * 2048 * 64;

  float mloc = -1e30f, zloc = 0.f, sploc = 0.f;
  int cnt = 0;

  // ---- pass A: dot, expA, sample, online softmax stats ----
  for (int mc = 0; mc < 64; ++mc) {
    for (int i = t; i < 2048; i += 256) Ks[i >> 6][i & 63] = Kg[kvbase + (size_t)mc * 2048 + i];
    for (int i = t; i < 512; i += 256) sktS[i >> 4][i & 15] = sktp[(size_t)mc * 512 + i];
    __syncthreads();

    const int m = mc * 32 + tm;
    f32x4 acc = {0.f, 0.f, 0.f, 0.f};
#pragma unroll
    for (int c = 0; c < 16; ++c) {
      const f32x4 kv = *(const f32x4*)&Ks[tm][4 * c];
      acc += qv[c] * kv;
    }
    const float s = (acc[0] + acc[1] + acc[2] + acc[3]) * 0.125f;

    double ea = 0.0;
#pragma unroll
    for (int k = 0; k < 16; ++k) ea += dqh[k] * sktS[tm][k];
    const int bit = ((double)nrow[m] < ea) ? 1 : 0;
    cnt += bit;
    const int msk = mkp[m];
    if (!msk) {
      if (s > mloc) { const float r = __expf(mloc - s); zloc *= r; sploc *= r; mloc = s; }
      const float e = __expf(s - mloc);
      zloc += e;
      if (bit) sploc += e;
    }
    sA[tn][m] = (f16)s;
    const unsigned long long ball = __ballot(bit);
    if (tm == 0) gb[tn][mc] = (unsigned int)(ball >> ((tn & 1) * 32));
    __syncthreads();
  }

  // ---- row stats combine ----
  redM[tn][tm] = mloc; redZ[tn][tm] = zloc; redP[tn][tm] = sploc;
  int c2 = cnt;
  c2 += __shfl_xor(c2, 1); c2 += __shfl_xor(c2, 2); c2 += __shfl_xor(c2, 4);
  c2 += __shfl_xor(c2, 8); c2 += __shfl_xor(c2, 16); c2 += __shfl_xor(c2, 32);
  if ((t & 63) == 0) spRed[t >> 6] = (float)c2;
  __syncthreads();
  if (t < ORO) {
    float M = -1e30f, Z = 0.f, SP = 0.f;
    for (int i = 0; i < 32; ++i) {
      const float Mi = redM[t][i];
      if (Mi > M) { const float r = __expf(M - Mi); Z *= r; SP *= r; M = Mi; }
      const float r2 = __expf(Mi - M);
      Z += redZ[t][i] * r2; SP += redP[t][i] * r2;
    }
    rowM[t] = M;
    // attn = g * exp(s-M) / max(SP, 1e-12*Z)  ==  ref p/max(sum p, 1e-12)
    rowScale[t] = 1.0f / fmaxf(SP, 1e-12f * Z);
  }
  if (t == 0) atomicAdd(&wsSP[h], spRed[0] + spRed[1] + spRed[2] + spRed[3]);
  __syncthreads();

  // ---- pass B1: finalize attn + write attn/graph as FLOAT32 ----
  for (int rr = 0; rr < ORO; ++rr) {
    const int base = t * 8;
    const f16x8 sv8 = *(const f16x8*)&sA[rr][base];
    const unsigned int word = gb[rr][base >> 5] >> (base & 31);
    const float inv = rowScale[rr], M = rowM[rr];
    f32x8 av, gv;
    f16x8 a8;
#pragma unroll
    for (int j = 0; j < 8; ++j) {
      const int bj = (word >> j) & 1;
      const int mj = mkp[base + j];
      const float a = (bj && !mj) ? __expf((float)sv8[j] - M) * inv : 0.f;
      av[j] = a;
      gv[j] = bj ? 1.0f : 0.0f;
      a8[j] = (f16)a;
    }
    *(f16x8*)&sA[rr][base] = a8;
    const size_t ro = ((size_t)bh * 2048 + n0 + rr) * 2048 + base;
    *(f32x8*)(AOUT + ro) = av;
    *(f32x8*)(GOUT + ro) = gv;
  }
  __syncthreads();

  // ---- pass B2: X = attn @ V, write f32 ----
  const int dq = tm & 15, mh = tm >> 4;
  f32x4 xa = {0.f, 0.f, 0.f, 0.f};
  for (int mc = 0; mc < 64; ++mc) {
    for (int i = t; i < 2048; i += 256) Ks[i >> 6][i & 63] = Vg[kvbase + (size_t)mc * 2048 + i];
    __syncthreads();
#pragma unroll
    for (int j = 0; j < 16; ++j) {
      const int mm = mh * 16 + j;
      const float a = (float)sA[tn][mc * 32 + mm];
      const f32x4 vv = *(const f32x4*)&Ks[mm][dq * 4];
      xa += a * vv;
    }
    __syncthreads();
  }
  if (mh == 1) *(f32x4*)&xh[tn][dq * 4] = xa;
  __syncthreads();
  if (mh == 0) {
    const f32x4 o = xa + *(const f32x4*)&xh[tn][dq * 4];
    *(f32x4*)(XOUT + ((size_t)bh * 2048 + n0 + tn) * 64 + dq * 4) = o;
  }
}

// ---------------- kFin: sparsity (f32) ----------------
__global__ void kFin(const float* __restrict__ wsSP, float* __restrict__ SPOUT) {
  const int t = threadIdx.x;
  if (t < 8) SPOUT[t] = wsSP[t] * (1.0f / 8388608.0f);  // /(2*2048*2048)
}

extern "C" void kernel_launch(void* const* d_in, const int* in_sizes, int n_in,
                              void* d_out, int out_size, void* d_ws, size_t ws_size,
                              hipStream_t stream) {
  const float* Q = (const float*)d_in[0];
  const float* K = (const float*)d_in[1];
  const float* V = (const float*)d_in[2];
  const int* mask = (const int*)d_in[3];
  const float* noise = (const float*)d_in[4];
  const float* emb = (const float*)d_in[5];
  const float* W1 = (const float*)d_in[6];
  const float* b1 = (const float*)d_in[7];
  const float* W2 = (const float*)d_in[8];
  const float* b2 = (const float*)d_in[9];
  const float* W3 = (const float*)d_in[10];
  const float* b3 = (const float*)d_in[11];

  char* ws = (char*)d_ws;
  double* wsS = (double*)(ws + 0);                 // 8*256 f64 = 16 KB
  float* wsSP = (float*)(ws + 16384);              // 8 f32
  double* QHAT = (double*)(ws + 32768);            // 4 MB
  double* SKT = (double*)(ws + 32768 + 4194304);   // 4 MB

  float* out = (float*)d_out;                      // FLOAT32 outputs
  float* XOUT = out;                               // 2*8*2048*64
  float* SPOUT = out + 2097152;                    // 8
  float* GOUT = out + 2097160;                     // 2*8*2048*2048
  float* AOUT = out + 69206024;                    // 2*8*2048*2048

  kS<<<8, 256, 0, stream>>>(emb, wsS, wsSP);
  kMLP<<<1024, 256, 0, stream>>>(Q, K, emb, W1, b1, W2, b2, W3, b3, wsS, QHAT, SKT);
  kMainO<<<dim3(256, 16), 256, 0, stream>>>(Q, mask, noise, QHAT, SKT, K, V, wsSP,
                                            XOUT, GOUT, AOUT);
  kFin<<<1, 64, 0, stream>>>(wsSP, SPOUT);
}

// Round 6
// 1036.148 us; speedup vs baseline: 2.0323x; 2.0323x over previous
//
#include <hip/hip_runtime.h>

// SBMAttention — round 6: fast MFMA main kernel, f32 outputs.
// Validated facts from round 5: outputs are FLOAT32; f64 sampling chain
// (kS/kMLP/expA) produces ZERO Bernoulli flips vs the np reference.
// kMain: per (bh, 16-row Q tile); each wave owns independent 32-col blocks
// (no barriers in main loop). QK^T + PV via mfma_f32_16x16x32_bf16.
// u = exp(dot/8)*g in swizzled bf16 LDS; attn = u/max(sum u,1e-12) (row max
// cancels); graph = u>0; X = (u@V)/sum.

typedef float  f32x4 __attribute__((ext_vector_type(4)));
typedef float  f32x8 __attribute__((ext_vector_type(8)));
typedef __bf16 bf16x8 __attribute__((ext_vector_type(8)));

__device__ __forceinline__ unsigned short f2bf(float f) {
  __bf16 b = (__bf16)f;
  return __builtin_bit_cast(unsigned short, b);
}

// ---------------- kS: cluster softmax (f64) — unchanged (validated) --------
__global__ __launch_bounds__(256) void kS(const float* __restrict__ emb,
                                          double* __restrict__ wsS,
                                          float* __restrict__ wsSP) {
  __shared__ double c[16][65];
  __shared__ double red[256];
  const int t = threadIdx.x, h = blockIdx.x;
  if (t == 0) wsSP[h] = 0.f;
  for (int i = t; i < 1024; i += 256) c[i >> 6][i & 63] = (double)emb[(size_t)h * 1024 + i];
  __syncthreads();
  const int k = t >> 4, j = t & 15;
  double acc = 0.0;
  for (int d = 0; d < 64; ++d) acc += c[k][d] * c[j][d];
  red[t] = acc; __syncthreads();
  for (int s = 128; s > 0; s >>= 1) { if (t < s) red[t] = fmax(red[t], red[t + s]); __syncthreads(); }
  const double mx = red[0]; __syncthreads();
  const double e = exp(acc - mx);
  red[t] = e; __syncthreads();
  for (int s = 128; s > 0; s >>= 1) { if (t < s) red[t] += red[t + s]; __syncthreads(); }
  wsS[h * 256 + t] = e / red[0];
}

// ---------------- kCvtV: V -> bf16 transposed VT[d][m] ----------------
__global__ __launch_bounds__(256) void kCvtV(const float* __restrict__ V,
                                             unsigned short* __restrict__ VT) {
  __shared__ float vt[128][65];
  const int t = threadIdx.x;
  const int bh = blockIdx.x, ch = blockIdx.y;
  const size_t base = ((size_t)bh * 2048 + ch * 128) * 64;
  for (int i = t; i < 8192; i += 256) vt[i >> 6][i & 63] = V[base + i];
  __syncthreads();
  const size_t vbase = (size_t)bh * 64 * 2048 + ch * 128;
  for (int i = t; i < 8192; i += 256) {
    const int d = i >> 7, mm = i & 127;
    VT[vbase + (size_t)d * 2048 + mm] = f2bf(vt[mm][d]);
  }
}

// ---------------- kMLP: proj + hats (f64) — unchanged (validated) ----------
__global__ __launch_bounds__(256) void kMLP(
    const float* __restrict__ Q, const float* __restrict__ K,
    const float* __restrict__ emb,
    const float* __restrict__ W1, const float* __restrict__ b1,
    const float* __restrict__ W2, const float* __restrict__ b2,
    const float* __restrict__ W3, const float* __restrict__ b3,
    const double* __restrict__ wsS,
    double* __restrict__ QHAT, double* __restrict__ SKT) {
  __shared__ double Xt[64][65];
  __shared__ float  Wl[64][65];
  __shared__ float  bsS[64];
  __shared__ float  cl[16][65];
  __shared__ double kh[64][17];
  __shared__ double Sl[256];

  const int t = threadIdx.x;
  const int blk = blockIdx.x;
  const int side = blk >> 9;
  const int idx = blk & 511;
  const int bh = idx >> 5;
  const int h = bh & 7;
  const int chunk = idx & 31;
  const size_t t0 = (size_t)bh * 2048 + (size_t)chunk * 64;

  const float* src = side ? K : Q;
  for (int i = t; i < 4096; i += 256) Xt[i >> 6][i & 63] = (double)src[t0 * 64 + i];

  const float* Ws[3] = {W1, W2, W3};
  const float* bs[3] = {b1, b2, b3};
  const int te = t & 15, tt = t >> 4;
  const int e0 = te * 4, tok0 = tt * 4;

  for (int l = 0; l < 3; ++l) {
    __syncthreads();
    for (int i = t; i < 4096; i += 256) Wl[i >> 6][i & 63] = Ws[l][i];
    if (t < 64) bsS[t] = bs[l][t];
    __syncthreads();
    double o[4][4];
#pragma unroll
    for (int i = 0; i < 4; ++i)
#pragma unroll
      for (int j = 0; j < 4; ++j) o[i][j] = 0.0;
    for (int d = 0; d < 64; ++d) {
      const double x0 = Xt[tok0 + 0][d], x1 = Xt[tok0 + 1][d], x2 = Xt[tok0 + 2][d], x3 = Xt[tok0 + 3][d];
      const double w0 = (double)Wl[e0 + 0][d], w1 = (double)Wl[e0 + 1][d];
      const double w2 = (double)Wl[e0 + 2][d], w3 = (double)Wl[e0 + 3][d];
      o[0][0] += x0 * w0; o[0][1] += x0 * w1; o[0][2] += x0 * w2; o[0][3] += x0 * w3;
      o[1][0] += x1 * w0; o[1][1] += x1 * w1; o[1][2] += x1 * w2; o[1][3] += x1 * w3;
      o[2][0] += x2 * w0; o[2][1] += x2 * w1; o[2][2] += x2 * w2; o[2][3] += x2 * w3;
      o[3][0] += x3 * w0; o[3][1] += x3 * w1; o[3][2] += x3 * w2; o[3][3] += x3 * w3;
    }
#pragma unroll
    for (int i = 0; i < 4; ++i)
#pragma unroll
      for (int j = 0; j < 4; ++j) {
        double v = o[i][j] + (double)bsS[e0 + j];
        if (l < 2) v = fmax(v, 0.0);
        o[i][j] = v;
      }
    __syncthreads();
#pragma unroll
    for (int i = 0; i < 4; ++i)
#pragma unroll
      for (int j = 0; j < 4; ++j) Xt[tok0 + i][e0 + j] = o[i][j];
  }
  __syncthreads();
  for (int i = t; i < 1024; i += 256) cl[i >> 6][i & 63] = emb[(size_t)h * 1024 + i];
  if (side) { for (int i = t; i < 256; i += 256) Sl[i] = wsS[h * 256 + i]; }
  __syncthreads();

  const int tok = t >> 2, k0 = (t & 3) * 4;
  double z[4] = {0.0, 0.0, 0.0, 0.0};
  for (int d = 0; d < 64; ++d) {
    const double xv = Xt[tok][d];
    z[0] += xv * (double)cl[k0 + 0][d]; z[1] += xv * (double)cl[k0 + 1][d];
    z[2] += xv * (double)cl[k0 + 2][d]; z[3] += xv * (double)cl[k0 + 3][d];
  }
  double hat[4];
#pragma unroll
  for (int j = 0; j < 4; ++j) hat[j] = 1.0 / (1.0 + exp(-z[j]));

  if (!side) {
#pragma unroll
    for (int j = 0; j < 4; ++j) QHAT[(t0 + tok) * 16 + k0 + j] = hat[j];
  } else {
    kh[tok][k0 + 0] = hat[0]; kh[tok][k0 + 1] = hat[1];
    kh[tok][k0 + 2] = hat[2]; kh[tok][k0 + 3] = hat[3];
    __syncthreads();
    double sk[4] = {0.0, 0.0, 0.0, 0.0};
    for (int jj = 0; jj < 16; ++jj) {
      const double kv = kh[tok][jj];
      sk[0] += Sl[(k0 + 0) * 16 + jj] * kv; sk[1] += Sl[(k0 + 1) * 16 + jj] * kv;
      sk[2] += Sl[(k0 + 2) * 16 + jj] * kv; sk[3] += Sl[(k0 + 3) * 16 + jj] * kv;
    }
#pragma unroll
    for (int j = 0; j < 4; ++j) SKT[(t0 + tok) * 16 + k0 + j] = sk[j];
  }
}

// ---------------- kMain: fused MFMA attention (f32 outputs) ----------------
__global__ __launch_bounds__(256) void kMain(
    const float* __restrict__ Q, const int* __restrict__ maskp,
    const float* __restrict__ noise,
    const double* __restrict__ qhat, const double* __restrict__ skt,
    const float* __restrict__ Kg, const unsigned short* __restrict__ VT,
    float* __restrict__ wsSP,
    float* __restrict__ XOUT, float* __restrict__ GOUT,
    float* __restrict__ AOUT) {
  __shared__ unsigned short uS[16 * 2048];   // 64KB, XOR-swizzled rows
  __shared__ double qhatS[16][17];
  __shared__ float xredS[16][65];
  __shared__ float dredS[4][16];
  __shared__ float dinvS[16];

  const int t = threadIdx.x;
  const int wave = t >> 6, lane = t & 63;
  const int bh = blockIdx.y;
  const int b = bh >> 3, h = bh & 7;
  const int n0 = blockIdx.x * 16;
  const int hi2 = lane >> 4;          // 0..3
  const int hi8 = hi2 << 3;
  const int g4 = hi2 << 2;            // acc row group base
  const int lm = lane & 15;

  qhatS[t >> 4][t & 15] = qhat[((size_t)bh * 2048 + n0 + (t >> 4)) * 16 + (t & 15)];
  for (int i = t; i < 16 * 65; i += 256) ((float*)xredS)[i] = 0.f;
  __syncthreads();

  // Q A-fragments (f32 -> bf16): lane holds A[row=lm][k = hi8 + hh*32 + 0..7]
  const float* qrow = Q + ((size_t)bh * 2048 + n0 + lm) * 64;
  bf16x8 aq[2];
#pragma unroll
  for (int hh = 0; hh < 2; ++hh) {
    const int d0 = hi8 + hh * 32;
    const f32x4 qa = *(const f32x4*)(qrow + d0);
    const f32x4 qb = *(const f32x4*)(qrow + d0 + 4);
    bf16x8 v;
    v[0] = (__bf16)qa[0]; v[1] = (__bf16)qa[1]; v[2] = (__bf16)qa[2]; v[3] = (__bf16)qa[3];
    v[4] = (__bf16)qb[0]; v[5] = (__bf16)qb[1]; v[6] = (__bf16)qb[2]; v[7] = (__bf16)qb[3];
    aq[hh] = v;
  }

  const float* kgp = Kg + (size_t)bh * 2048 * 64;
  const unsigned short* vtp = VT + (size_t)bh * 64 * 2048;
  const float* nzp = noise + ((size_t)bh * 2048 + n0) * 2048;
  const double* sktp = skt + (size_t)bh * 2048 * 16;
  const int* mkp = maskp + b * 2048;

  float dsum[4] = {0.f, 0.f, 0.f, 0.f};
  int gcnt = 0;
  f32x4 xacc[4];
#pragma unroll
  for (int td = 0; td < 4; ++td) xacc[td] = (f32x4){0.f, 0.f, 0.f, 0.f};

  for (int it = 0; it < 16; ++it) {
    const int mb = ((it << 2) + wave) << 5;  // this wave's 32-col block

    // ---- QK^T via MFMA (two 16x16 tiles), K loaded f32->bf16 ----
    f32x4 st[2];
#pragma unroll
    for (int tt = 0; tt < 2; ++tt) {
      const float* krow = kgp + (size_t)(mb + tt * 16 + lm) * 64;
      const f32x4 ka = *(const f32x4*)(krow + hi8);
      const f32x4 kb = *(const f32x4*)(krow + hi8 + 4);
      const f32x4 kc = *(const f32x4*)(krow + 32 + hi8);
      const f32x4 kd = *(const f32x4*)(krow + 32 + hi8 + 4);
      bf16x8 b0, b1;
      b0[0] = (__bf16)ka[0]; b0[1] = (__bf16)ka[1]; b0[2] = (__bf16)ka[2]; b0[3] = (__bf16)ka[3];
      b0[4] = (__bf16)kb[0]; b0[5] = (__bf16)kb[1]; b0[6] = (__bf16)kb[2]; b0[7] = (__bf16)kb[3];
      b1[0] = (__bf16)kc[0]; b1[1] = (__bf16)kc[1]; b1[2] = (__bf16)kc[2]; b1[3] = (__bf16)kc[3];
      b1[4] = (__bf16)kd[0]; b1[5] = (__bf16)kd[1]; b1[6] = (__bf16)kd[2]; b1[7] = (__bf16)kd[3];
      f32x4 acc = (f32x4){0.f, 0.f, 0.f, 0.f};
      acc = __builtin_amdgcn_mfma_f32_16x16x32_bf16(aq[0], b0, acc, 0, 0, 0);
      acc = __builtin_amdgcn_mfma_f32_16x16x32_bf16(aq[1], b1, acc, 0, 0, 0);
      st[tt] = acc;
    }

    // ---- expA (f64) + sample + u -> swizzled LDS, one tt at a time ----
#pragma unroll
    for (int tt = 0; tt < 2; ++tt) {
      const int m = mb + tt * 16 + lm;
      const double* sp = sktp + (size_t)m * 16;
      double ea[4] = {0.0, 0.0, 0.0, 0.0};
#pragma unroll
      for (int k = 0; k < 16; ++k) {
        const double sv = sp[k];
        ea[0] += qhatS[g4 + 0][k] * sv; ea[1] += qhatS[g4 + 1][k] * sv;
        ea[2] += qhatS[g4 + 2][k] * sv; ea[3] += qhatS[g4 + 3][k] * sv;
      }
      const int mv = mkp[m];
      const f32x4 sv4 = st[tt];
#pragma unroll
      for (int r = 0; r < 4; ++r) {
        const int nl = g4 + r;
        const float nz = nzp[(size_t)nl * 2048 + m];
        const float e = __expf(sv4[r] * 0.125f);
        const int g = ((double)nz < ea[r]) ? 1 : 0;
        gcnt += g;
        float u = g ? e : 0.f;
        if (mv == 1) u = 0.f;
        dsum[r] += u;
        uS[nl * 2048 + (m ^ ((nl & 7) << 3))] = f2bf(u);
      }
    }

    // ---- PV via MFMA: X += u @ V (reads this wave's own fresh block) ----
    {
      const int me = mb + hi8;
      const bf16x8 ua = *(const bf16x8*)&uS[lm * 2048 + (me ^ ((lm & 7) << 3))];
#pragma unroll
      for (int td = 0; td < 4; ++td) {
        const bf16x8 vb = *(const bf16x8*)(vtp + (size_t)(td * 16 + lm) * 2048 + me);
        xacc[td] = __builtin_amdgcn_mfma_f32_16x16x32_bf16(ua, vb, xacc[td], 0, 0, 0);
      }
    }
  }

  // ---- denominator: reduce over 16 lanes sharing a row group ----
#pragma unroll
  for (int r = 0; r < 4; ++r) {
    float v = dsum[r];
    v += __shfl_xor(v, 1); v += __shfl_xor(v, 2); v += __shfl_xor(v, 4); v += __shfl_xor(v, 8);
    if (lm == 0) dredS[wave][g4 + r] = v;
  }
  {
    int c = gcnt;
    c += __shfl_xor(c, 1); c += __shfl_xor(c, 2); c += __shfl_xor(c, 4);
    c += __shfl_xor(c, 8); c += __shfl_xor(c, 16); c += __shfl_xor(c, 32);
    if (lane == 0) atomicAdd(&wsSP[h], (float)c);
  }

  // ---- X cross-wave reduce (deterministic staged adds) ----
  for (int w = 0; w < 4; ++w) {
    if (wave == w) {
#pragma unroll
      for (int td = 0; td < 4; ++td)
#pragma unroll
        for (int r = 0; r < 4; ++r) xredS[g4 + r][td * 16 + lm] += xacc[td][r];
    }
    __syncthreads();
  }
  if (t < 16) {
    const float dv = dredS[0][t] + dredS[1][t] + dredS[2][t] + dredS[3][t];
    dinvS[t] = 1.0f / fmaxf(dv, 1e-12f);
  }
  __syncthreads();

  // ---- write X (f32) ----
  for (int i = t; i < 1024; i += 256) {
    const int nl = i >> 6, d = i & 63;
    XOUT[((size_t)bh * 2048 + n0 + nl) * 64 + d] = xredS[nl][d] * dinvS[nl];
  }

  // ---- write attn + graph (f32x8, coalesced from LDS) ----
  const size_t rowbase = (size_t)bh * 2048 + n0;
#pragma unroll
  for (int rr = 0; rr < 4; ++rr) {
    const int nl = wave * 4 + rr;
    const float inv = dinvS[nl];
    const size_t ro = (rowbase + nl) * 2048;
#pragma unroll
    for (int c = 0; c < 4; ++c) {
      const int me = c * 512 + lane * 8;
      const unsigned short* up = &uS[nl * 2048 + (me ^ ((nl & 7) << 3))];
      f32x8 av, gv;
#pragma unroll
      for (int j = 0; j < 8; ++j) {
        const float f = (float)__builtin_bit_cast(__bf16, up[j]);
        av[j] = f * inv;
        gv[j] = (f > 0.f) ? 1.0f : 0.0f;
      }
      *(f32x8*)(AOUT + ro + me) = av;
      *(f32x8*)(GOUT + ro + me) = gv;
    }
  }
}

// ---------------- kFin: sparsity (f32) ----------------
__global__ void kFin(const float* __restrict__ wsSP, float* __restrict__ SPOUT) {
  const int t = threadIdx.x;
  if (t < 8) SPOUT[t] = wsSP[t] * (1.0f / 8388608.0f);  // /(2*2048*2048)
}

extern "C" void kernel_launch(void* const* d_in, const int* in_sizes, int n_in,
                              void* d_out, int out_size, void* d_ws, size_t ws_size,
                              hipStream_t stream) {
  const float* Q = (const float*)d_in[0];
  const float* K = (const float*)d_in[1];
  const float* V = (const float*)d_in[2];
  const int* mask = (const int*)d_in[3];
  const float* noise = (const float*)d_in[4];
  const float* emb = (const float*)d_in[5];
  const float* W1 = (const float*)d_in[6];
  const float* b1 = (const float*)d_in[7];
  const float* W2 = (const float*)d_in[8];
  const float* b2 = (const float*)d_in[9];
  const float* W3 = (const float*)d_in[10];
  const float* b3 = (const float*)d_in[11];

  char* ws = (char*)d_ws;
  double* wsS = (double*)(ws + 0);                          // 16 KB
  float* wsSP = (float*)(ws + 16384);                       // 8 f32
  double* QHAT = (double*)(ws + 32768);                     // 4 MB f64
  double* SKT  = (double*)(ws + 32768 + 4194304);           // 4 MB f64
  unsigned short* VT = (unsigned short*)(ws + 32768 + 8388608);  // 4 MB bf16

  float* out = (float*)d_out;                     // FLOAT32 outputs
  float* XOUT = out;                              // 2*8*2048*64
  float* SPOUT = out + 2097152;                   // 8
  float* GOUT = out + 2097160;                    // 2*8*2048*2048
  float* AOUT = out + 69206024;                   // 2*8*2048*2048

  kS<<<8, 256, 0, stream>>>(emb, wsS, wsSP);
  kCvtV<<<dim3(16, 16), 256, 0, stream>>>(V, VT);
  kMLP<<<1024, 256, 0, stream>>>(Q, K, emb, W1, b1, W2, b2, W3, b3, wsS, QHAT, SKT);
  kMain<<<dim3(128, 16), 256, 0, stream>>>(Q, mask, noise, QHAT, SKT, K, VT, wsSP,
                                           XOUT, GOUT, AOUT);
  kFin<<<1, 64, 0, stream>>>(wsSP, SPOUT);
}

// Round 7
// 1000.390 us; speedup vs baseline: 2.1049x; 1.0357x over previous
//
#include <hip/hip_runtime.h>

// SBMAttention — round 7: low-LDS two-phase kMain for occupancy.
// r6 failure mode: 72KB LDS -> 1 block/CU -> 1 wave/SIMD -> latency-bound at
// 794 GB/s. This round removes the 64KB u-row buffer: phase 1 computes
// Bernoulli bits (4KB LDS) + exact row denominators; phase 2 recomputes QK^T
// (deterministic) and rebuilds u per 32-col block in a 1KB/wave staging tile,
// feeding PV MFMA and coalesced f32x8 attn writes. Graph written from bits.
// Sampling chain (kS/kMLP f64) unchanged (validated: zero flips).

typedef float  f32x4 __attribute__((ext_vector_type(4)));
typedef float  f32x8 __attribute__((ext_vector_type(8)));
typedef double f64x2 __attribute__((ext_vector_type(2)));
typedef __bf16 bf16x8 __attribute__((ext_vector_type(8)));

__device__ __forceinline__ unsigned short f2bf(float f) {
  __bf16 b = (__bf16)f;
  return __builtin_bit_cast(unsigned short, b);
}

// ---------------- kS: cluster softmax (f64) — validated ----------------
__global__ __launch_bounds__(256) void kS(const float* __restrict__ emb,
                                          double* __restrict__ wsS,
                                          float* __restrict__ wsSP) {
  __shared__ double c[16][65];
  __shared__ double red[256];
  const int t = threadIdx.x, h = blockIdx.x;
  if (t == 0) wsSP[h] = 0.f;
  for (int i = t; i < 1024; i += 256) c[i >> 6][i & 63] = (double)emb[(size_t)h * 1024 + i];
  __syncthreads();
  const int k = t >> 4, j = t & 15;
  double acc = 0.0;
  for (int d = 0; d < 64; ++d) acc += c[k][d] * c[j][d];
  red[t] = acc; __syncthreads();
  for (int s = 128; s > 0; s >>= 1) { if (t < s) red[t] = fmax(red[t], red[t + s]); __syncthreads(); }
  const double mx = red[0]; __syncthreads();
  const double e = exp(acc - mx);
  red[t] = e; __syncthreads();
  for (int s = 128; s > 0; s >>= 1) { if (t < s) red[t] += red[t + s]; __syncthreads(); }
  wsS[h * 256 + t] = e / red[0];
}

// ---------------- kCvtV: V -> bf16 transposed VT[d][m] ----------------
__global__ __launch_bounds__(256) void kCvtV(const float* __restrict__ V,
                                             unsigned short* __restrict__ VT) {
  __shared__ float vt[128][65];
  const int t = threadIdx.x;
  const int bh = blockIdx.x, ch = blockIdx.y;
  const size_t base = ((size_t)bh * 2048 + ch * 128) * 64;
  for (int i = t; i < 8192; i += 256) vt[i >> 6][i & 63] = V[base + i];
  __syncthreads();
  const size_t vbase = (size_t)bh * 64 * 2048 + ch * 128;
  for (int i = t; i < 8192; i += 256) {
    const int d = i >> 7, mm = i & 127;
    VT[vbase + (size_t)d * 2048 + mm] = f2bf(vt[mm][d]);
  }
}

// ---------------- kMLP: proj + hats (f64) — validated ----------------
__global__ __launch_bounds__(256) void kMLP(
    const float* __restrict__ Q, const float* __restrict__ K,
    const float* __restrict__ emb,
    const float* __restrict__ W1, const float* __restrict__ b1,
    const float* __restrict__ W2, const float* __restrict__ b2,
    const float* __restrict__ W3, const float* __restrict__ b3,
    const double* __restrict__ wsS,
    double* __restrict__ QHAT, double* __restrict__ SKT) {
  __shared__ double Xt[64][65];
  __shared__ float  Wl[64][65];
  __shared__ float  bsS[64];
  __shared__ float  cl[16][65];
  __shared__ double kh[64][17];
  __shared__ double Sl[256];

  const int t = threadIdx.x;
  const int blk = blockIdx.x;
  const int side = blk >> 9;
  const int idx = blk & 511;
  const int bh = idx >> 5;
  const int h = bh & 7;
  const int chunk = idx & 31;
  const size_t t0 = (size_t)bh * 2048 + (size_t)chunk * 64;

  const float* src = side ? K : Q;
  for (int i = t; i < 4096; i += 256) Xt[i >> 6][i & 63] = (double)src[t0 * 64 + i];

  const float* Ws[3] = {W1, W2, W3};
  const float* bs[3] = {b1, b2, b3};
  const int te = t & 15, tt = t >> 4;
  const int e0 = te * 4, tok0 = tt * 4;

  for (int l = 0; l < 3; ++l) {
    __syncthreads();
    for (int i = t; i < 4096; i += 256) Wl[i >> 6][i & 63] = Ws[l][i];
    if (t < 64) bsS[t] = bs[l][t];
    __syncthreads();
    double o[4][4];
#pragma unroll
    for (int i = 0; i < 4; ++i)
#pragma unroll
      for (int j = 0; j < 4; ++j) o[i][j] = 0.0;
    for (int d = 0; d < 64; ++d) {
      const double x0 = Xt[tok0 + 0][d], x1 = Xt[tok0 + 1][d], x2 = Xt[tok0 + 2][d], x3 = Xt[tok0 + 3][d];
      const double w0 = (double)Wl[e0 + 0][d], w1 = (double)Wl[e0 + 1][d];
      const double w2 = (double)Wl[e0 + 2][d], w3 = (double)Wl[e0 + 3][d];
      o[0][0] += x0 * w0; o[0][1] += x0 * w1; o[0][2] += x0 * w2; o[0][3] += x0 * w3;
      o[1][0] += x1 * w0; o[1][1] += x1 * w1; o[1][2] += x1 * w2; o[1][3] += x1 * w3;
      o[2][0] += x2 * w0; o[2][1] += x2 * w1; o[2][2] += x2 * w2; o[2][3] += x2 * w3;
      o[3][0] += x3 * w0; o[3][1] += x3 * w1; o[3][2] += x3 * w2; o[3][3] += x3 * w3;
    }
#pragma unroll
    for (int i = 0; i < 4; ++i)
#pragma unroll
      for (int j = 0; j < 4; ++j) {
        double v = o[i][j] + (double)bsS[e0 + j];
        if (l < 2) v = fmax(v, 0.0);
        o[i][j] = v;
      }
    __syncthreads();
#pragma unroll
    for (int i = 0; i < 4; ++i)
#pragma unroll
      for (int j = 0; j < 4; ++j) Xt[tok0 + i][e0 + j] = o[i][j];
  }
  __syncthreads();
  for (int i = t; i < 1024; i += 256) cl[i >> 6][i & 63] = emb[(size_t)h * 1024 + i];
  if (side) { for (int i = t; i < 256; i += 256) Sl[i] = wsS[h * 256 + i]; }
  __syncthreads();

  const int tok = t >> 2, k0 = (t & 3) * 4;
  double z[4] = {0.0, 0.0, 0.0, 0.0};
  for (int d = 0; d < 64; ++d) {
    const double xv = Xt[tok][d];
    z[0] += xv * (double)cl[k0 + 0][d]; z[1] += xv * (double)cl[k0 + 1][d];
    z[2] += xv * (double)cl[k0 + 2][d]; z[3] += xv * (double)cl[k0 + 3][d];
  }
  double hat[4];
#pragma unroll
  for (int j = 0; j < 4; ++j) hat[j] = 1.0 / (1.0 + exp(-z[j]));

  if (!side) {
#pragma unroll
    for (int j = 0; j < 4; ++j) QHAT[(t0 + tok) * 16 + k0 + j] = hat[j];
  } else {
    kh[tok][k0 + 0] = hat[0]; kh[tok][k0 + 1] = hat[1];
    kh[tok][k0 + 2] = hat[2]; kh[tok][k0 + 3] = hat[3];
    __syncthreads();
    double sk[4] = {0.0, 0.0, 0.0, 0.0};
    for (int jj = 0; jj < 16; ++jj) {
      const double kv = kh[tok][jj];
      sk[0] += Sl[(k0 + 0) * 16 + jj] * kv; sk[1] += Sl[(k0 + 1) * 16 + jj] * kv;
      sk[2] += Sl[(k0 + 2) * 16 + jj] * kv; sk[3] += Sl[(k0 + 3) * 16 + jj] * kv;
    }
#pragma unroll
    for (int j = 0; j < 4; ++j) SKT[(t0 + tok) * 16 + k0 + j] = sk[j];
  }
}

// ---------------- kMain: two-phase fused attention (low LDS) ----------------
__global__ __launch_bounds__(256) void kMain(
    const float* __restrict__ Q, const int* __restrict__ maskp,
    const float* __restrict__ noise,
    const double* __restrict__ qhat, const double* __restrict__ skt,
    const float* __restrict__ Kg, const unsigned short* __restrict__ VT,
    float* __restrict__ wsSP,
    float* __restrict__ XOUT, float* __restrict__ GOUT,
    float* __restrict__ AOUT) {
  __shared__ double qhatS[16][17];               // 2176 B
  __shared__ unsigned short gbitS[16][128];      // 4 KB: bit (m&15) of [row][m>>4]
  __shared__ unsigned short stageS[4][16][32];   // 4 KB: per-wave u tile (bf16)
  __shared__ float dredS[4][16];                 // 256 B
  __shared__ float dinvS[16];                    // 64 B
  __shared__ float xredS[16][68];                // 4352 B

  const int t = threadIdx.x;
  const int wave = t >> 6, lane = t & 63;
  const int bh = blockIdx.y;
  const int b = bh >> 3, h = bh & 7;
  const int n0 = blockIdx.x * 16;
  const int hi2 = lane >> 4;          // 0..3
  const int hi8 = hi2 << 3;
  const int g4 = hi2 << 2;
  const int lm = lane & 15;

  qhatS[t >> 4][t & 15] = qhat[((size_t)bh * 2048 + n0 + (t >> 4)) * 16 + (t & 15)];
  for (int i = t; i < 16 * 68; i += 256) ((float*)xredS)[i] = 0.f;
  __syncthreads();

  // Q A-fragments (f32 -> bf16): lane holds A[row=lm][k = hi8 + hh*32 + 0..7]
  const float* qrow = Q + ((size_t)bh * 2048 + n0 + lm) * 64;
  bf16x8 aq[2];
#pragma unroll
  for (int hh = 0; hh < 2; ++hh) {
    const int d0 = hi8 + hh * 32;
    const f32x4 qa = *(const f32x4*)(qrow + d0);
    const f32x4 qb = *(const f32x4*)(qrow + d0 + 4);
    bf16x8 v;
    v[0] = (__bf16)qa[0]; v[1] = (__bf16)qa[1]; v[2] = (__bf16)qa[2]; v[3] = (__bf16)qa[3];
    v[4] = (__bf16)qb[0]; v[5] = (__bf16)qb[1]; v[6] = (__bf16)qb[2]; v[7] = (__bf16)qb[3];
    aq[hh] = v;
  }

  const float* kgp = Kg + (size_t)bh * 2048 * 64;
  const unsigned short* vtp = VT + (size_t)bh * 64 * 2048;
  const float* nzp = noise + ((size_t)bh * 2048 + n0) * 2048;
  const double* sktp = skt + (size_t)bh * 2048 * 16;
  const int* mkp = maskp + b * 2048;

  // ================= PHASE 1: bits + denominators =================
  float dsum[4] = {0.f, 0.f, 0.f, 0.f};
  int gcnt = 0;

  for (int it = 0; it < 16; ++it) {
    const int mb = ((it << 2) + wave) << 5;

    // QK^T via MFMA (two 16x16 tiles), K f32 -> bf16
    f32x4 st[2];
#pragma unroll
    for (int tt = 0; tt < 2; ++tt) {
      const float* krow = kgp + (size_t)(mb + tt * 16 + lm) * 64;
      const f32x4 ka = *(const f32x4*)(krow + hi8);
      const f32x4 kb = *(const f32x4*)(krow + hi8 + 4);
      const f32x4 kc = *(const f32x4*)(krow + 32 + hi8);
      const f32x4 kd = *(const f32x4*)(krow + 32 + hi8 + 4);
      bf16x8 b0, b1;
      b0[0] = (__bf16)ka[0]; b0[1] = (__bf16)ka[1]; b0[2] = (__bf16)ka[2]; b0[3] = (__bf16)ka[3];
      b0[4] = (__bf16)kb[0]; b0[5] = (__bf16)kb[1]; b0[6] = (__bf16)kb[2]; b0[7] = (__bf16)kb[3];
      b1[0] = (__bf16)kc[0]; b1[1] = (__bf16)kc[1]; b1[2] = (__bf16)kc[2]; b1[3] = (__bf16)kc[3];
      b1[4] = (__bf16)kd[0]; b1[5] = (__bf16)kd[1]; b1[6] = (__bf16)kd[2]; b1[7] = (__bf16)kd[3];
      f32x4 acc = (f32x4){0.f, 0.f, 0.f, 0.f};
      acc = __builtin_amdgcn_mfma_f32_16x16x32_bf16(aq[0], b0, acc, 0, 0, 0);
      acc = __builtin_amdgcn_mfma_f32_16x16x32_bf16(aq[1], b1, acc, 0, 0, 0);
      st[tt] = acc;
    }

#pragma unroll
    for (int tt = 0; tt < 2; ++tt) {
      const int m = mb + tt * 16 + lm;
      const double* sp = sktp + (size_t)m * 16;
      double skv[16];
#pragma unroll
      for (int q = 0; q < 8; ++q) *(f64x2*)(skv + 2 * q) = *(const f64x2*)(sp + 2 * q);
      double ea[4] = {0.0, 0.0, 0.0, 0.0};
#pragma unroll
      for (int k = 0; k < 16; ++k) {
        const double sv = skv[k];
        ea[0] += qhatS[g4 + 0][k] * sv; ea[1] += qhatS[g4 + 1][k] * sv;
        ea[2] += qhatS[g4 + 2][k] * sv; ea[3] += qhatS[g4 + 3][k] * sv;
      }
      const int mv = mkp[m];
      const f32x4 sv4 = st[tt];
#pragma unroll
      for (int r = 0; r < 4; ++r) {
        const float nz = nzp[(size_t)(g4 + r) * 2048 + m];
        const int g = ((double)nz < ea[r]) ? 1 : 0;
        gcnt += g;
        if (g && !mv) dsum[r] += __expf(sv4[r] * 0.125f);
        const unsigned long long ball = __ballot(g);
        if (lm == 0) gbitS[g4 + r][(mb + tt * 16) >> 4] = (unsigned short)(ball >> (hi2 * 16));
      }
    }
  }

  // row denominators
#pragma unroll
  for (int r = 0; r < 4; ++r) {
    float v = dsum[r];
    v += __shfl_xor(v, 1); v += __shfl_xor(v, 2); v += __shfl_xor(v, 4); v += __shfl_xor(v, 8);
    if (lm == 0) dredS[wave][g4 + r] = v;
  }
  {
    int c = gcnt;
    c += __shfl_xor(c, 1); c += __shfl_xor(c, 2); c += __shfl_xor(c, 4);
    c += __shfl_xor(c, 8); c += __shfl_xor(c, 16); c += __shfl_xor(c, 32);
    if (lane == 0) atomicAdd(&wsSP[h], (float)c);
  }
  __syncthreads();
  if (t < 16) {
    const float dv = dredS[0][t] + dredS[1][t] + dredS[2][t] + dredS[3][t];
    dinvS[t] = 1.0f / fmaxf(dv, 1e-12f);
  }
  __syncthreads();

  // ================= PHASE 2: u rebuild, PV, attn writes =================
  const size_t rowbase = (size_t)bh * 2048 + n0;
  f32x4 xacc[4];
#pragma unroll
  for (int td = 0; td < 4; ++td) xacc[td] = (f32x4){0.f, 0.f, 0.f, 0.f};

  for (int it = 0; it < 16; ++it) {
    const int mb = ((it << 2) + wave) << 5;

    // recompute QK^T (bit-identical to phase 1)
    f32x4 st[2];
#pragma unroll
    for (int tt = 0; tt < 2; ++tt) {
      const float* krow = kgp + (size_t)(mb + tt * 16 + lm) * 64;
      const f32x4 ka = *(const f32x4*)(krow + hi8);
      const f32x4 kb = *(const f32x4*)(krow + hi8 + 4);
      const f32x4 kc = *(const f32x4*)(krow + 32 + hi8);
      const f32x4 kd = *(const f32x4*)(krow + 32 + hi8 + 4);
      bf16x8 b0, b1;
      b0[0] = (__bf16)ka[0]; b0[1] = (__bf16)ka[1]; b0[2] = (__bf16)ka[2]; b0[3] = (__bf16)ka[3];
      b0[4] = (__bf16)kb[0]; b0[5] = (__bf16)kb[1]; b0[6] = (__bf16)kb[2]; b0[7] = (__bf16)kb[3];
      b1[0] = (__bf16)kc[0]; b1[1] = (__bf16)kc[1]; b1[2] = (__bf16)kc[2]; b1[3] = (__bf16)kc[3];
      b1[4] = (__bf16)kd[0]; b1[5] = (__bf16)kd[1]; b1[6] = (__bf16)kd[2]; b1[7] = (__bf16)kd[3];
      f32x4 acc = (f32x4){0.f, 0.f, 0.f, 0.f};
      acc = __builtin_amdgcn_mfma_f32_16x16x32_bf16(aq[0], b0, acc, 0, 0, 0);
      acc = __builtin_amdgcn_mfma_f32_16x16x32_bf16(aq[1], b1, acc, 0, 0, 0);
      st[tt] = acc;
    }

    // rebuild u and stage (XOR-swizzled on 8-u16 slots by row>>2)
#pragma unroll
    for (int tt = 0; tt < 2; ++tt) {
      const int m = mb + tt * 16 + lm;
      const int mv = mkp[m];
      const f32x4 sv4 = st[tt];
      const int wcol = (mb + tt * 16) >> 4;
#pragma unroll
      for (int r = 0; r < 4; ++r) {
        const int row = g4 + r;
        const unsigned short w = gbitS[row][wcol];
        const int g = (w >> lm) & 1;
        const float u = (g && !mv) ? __expf(sv4[r] * 0.125f) : 0.f;
        const int col = tt * 16 + lm;
        stageS[wave][row][col ^ (((row >> 2) & 3) << 3)] = f2bf(u);
      }
    }

    // PV MFMA from staged A-fragments
    {
      const int rdcol = hi8 ^ (((lm >> 2) & 3) << 3);
      const bf16x8 ua = *(const bf16x8*)&stageS[wave][lm][rdcol];
#pragma unroll
      for (int td = 0; td < 4; ++td) {
        const bf16x8 vb = *(const bf16x8*)(vtp + (size_t)(td * 16 + lm) * 2048 + mb + hi8);
        xacc[td] = __builtin_amdgcn_mfma_f32_16x16x32_bf16(ua, vb, xacc[td], 0, 0, 0);
      }
    }

    // coalesced attn write for this 16x32 block
    {
      const int row = lane >> 2, q = lane & 3;
      const int rc = (q * 8) ^ (((row >> 2) & 3) << 3);
      const unsigned short* up = &stageS[wave][row][rc];
      const float inv = dinvS[row];
      f32x8 av;
#pragma unroll
      for (int j = 0; j < 8; ++j) av[j] = (float)__builtin_bit_cast(__bf16, up[j]) * inv;
      *(f32x8*)(AOUT + (rowbase + row) * 2048 + mb + q * 8) = av;
    }
  }

  // ---- X cross-wave reduce + write ----
  for (int w = 0; w < 4; ++w) {
    if (wave == w) {
#pragma unroll
      for (int td = 0; td < 4; ++td)
#pragma unroll
        for (int r = 0; r < 4; ++r) xredS[g4 + r][td * 16 + lm] += xacc[td][r];
    }
    __syncthreads();
  }
  for (int i = t; i < 1024; i += 256) {
    const int nl = i >> 6, d = i & 63;
    XOUT[(rowbase + nl) * 64 + d] = xredS[nl][d] * dinvS[nl];
  }

  // ---- graph write from bits (coalesced f32x8) ----
  for (int i = t; i < 4096; i += 256) {
    const int row = i >> 8;
    const int c8 = (i & 255) * 8;
    const unsigned short w = gbitS[row][c8 >> 4];
    const int bits = (w >> (c8 & 15)) & 0xFF;
    f32x8 gv;
#pragma unroll
    for (int j = 0; j < 8; ++j) gv[j] = ((bits >> j) & 1) ? 1.0f : 0.0f;
    *(f32x8*)(GOUT + (rowbase + row) * 2048 + c8) = gv;
  }
}

// ---------------- kFin: sparsity (f32) ----------------
__global__ void kFin(const float* __restrict__ wsSP, float* __restrict__ SPOUT) {
  const int t = threadIdx.x;
  if (t < 8) SPOUT[t] = wsSP[t] * (1.0f / 8388608.0f);  // /(2*2048*2048)
}

extern "C" void kernel_launch(void* const* d_in, const int* in_sizes, int n_in,
                              void* d_out, int out_size, void* d_ws, size_t ws_size,
                              hipStream_t stream) {
  const float* Q = (const float*)d_in[0];
  const float* K = (const float*)d_in[1];
  const float* V = (const float*)d_in[2];
  const int* mask = (const int*)d_in[3];
  const float* noise = (const float*)d_in[4];
  const float* emb = (const float*)d_in[5];
  const float* W1 = (const float*)d_in[6];
  const float* b1 = (const float*)d_in[7];
  const float* W2 = (const float*)d_in[8];
  const float* b2 = (const float*)d_in[9];
  const float* W3 = (const float*)d_in[10];
  const float* b3 = (const float*)d_in[11];

  char* ws = (char*)d_ws;
  double* wsS = (double*)(ws + 0);                          // 16 KB
  float* wsSP = (float*)(ws + 16384);                       // 8 f32
  double* QHAT = (double*)(ws + 32768);                     // 4 MB f64
  double* SKT  = (double*)(ws + 32768 + 4194304);           // 4 MB f64
  unsigned short* VT = (unsigned short*)(ws + 32768 + 8388608);  // 4 MB bf16

  float* out = (float*)d_out;                     // FLOAT32 outputs
  float* XOUT = out;                              // 2*8*2048*64
  float* SPOUT = out + 2097152;                   // 8
  float* GOUT = out + 2097160;                    // 2*8*2048*2048
  float* AOUT = out + 69206024;                   // 2*8*2048*2048

  kS<<<8, 256, 0, stream>>>(emb, wsS, wsSP);
  kCvtV<<<dim3(16, 16), 256, 0, stream>>>(V, VT);
  kMLP<<<1024, 256, 0, stream>>>(Q, K, emb, W1, b1, W2, b2, W3, b3, wsS, QHAT, SKT);
  kMain<<<dim3(128, 16), 256, 0, stream>>>(Q, mask, noise, QHAT, SKT, K, VT, wsSP,
                                           XOUT, GOUT, AOUT);
  kFin<<<1, 64, 0, stream>>>(wsSP, SPOUT);
}

// Round 8
// 553.415 us; speedup vs baseline: 3.8050x; 1.8077x over previous
//
#include <hip/hip_runtime.h>

// SBMAttention — round 8: split kMain into kSample (bits/graph, f64, no MFMA)
// + kAttn (MFMA attention, no f64). r7 evidence: occupancy stuck at 12%
// (register-bound: f64 chains + MFMA accs in one kernel), HBM 850 GB/s.
// kSample: lane owns column m (skt[m] in regs), rows broadcast from LDS,
// noise row-coalesced, bits -> ws (8.4 MB), graph written here.
// kAttn: two-phase (denom, then PV+attn) recomputing QK^T from bf16 K; bits
// from LDS. ws aliasing keeps footprint at the proven 16.03 MiB:
//   [wsS 16K | wsSP | QHAT 4M -> KB 4M | SKT 4M -> VT 4M | GB 8M]
// Launch order: kS, kMLP, kSample, kCvt (overwrites QHAT/SKT), kAttn, kFin.

typedef float  f32x4 __attribute__((ext_vector_type(4)));
typedef float  f32x8 __attribute__((ext_vector_type(8)));
typedef double f64x2 __attribute__((ext_vector_type(2)));
typedef __bf16 bf16x8 __attribute__((ext_vector_type(8)));

__device__ __forceinline__ unsigned short f2bf(float f) {
  __bf16 b = (__bf16)f;
  return __builtin_bit_cast(unsigned short, b);
}

// ---------------- kS: cluster softmax (f64) — validated ----------------
__global__ __launch_bounds__(256) void kS(const float* __restrict__ emb,
                                          double* __restrict__ wsS,
                                          float* __restrict__ wsSP) {
  __shared__ double c[16][65];
  __shared__ double red[256];
  const int t = threadIdx.x, h = blockIdx.x;
  if (t == 0) wsSP[h] = 0.f;
  for (int i = t; i < 1024; i += 256) c[i >> 6][i & 63] = (double)emb[(size_t)h * 1024 + i];
  __syncthreads();
  const int k = t >> 4, j = t & 15;
  double acc = 0.0;
  for (int d = 0; d < 64; ++d) acc += c[k][d] * c[j][d];
  red[t] = acc; __syncthreads();
  for (int s = 128; s > 0; s >>= 1) { if (t < s) red[t] = fmax(red[t], red[t + s]); __syncthreads(); }
  const double mx = red[0]; __syncthreads();
  const double e = exp(acc - mx);
  red[t] = e; __syncthreads();
  for (int s = 128; s > 0; s >>= 1) { if (t < s) red[t] += red[t + s]; __syncthreads(); }
  wsS[h * 256 + t] = e / red[0];
}

// ---------------- kMLP: proj + hats (f64) — validated ----------------
__global__ __launch_bounds__(256) void kMLP(
    const float* __restrict__ Q, const float* __restrict__ K,
    const float* __restrict__ emb,
    const float* __restrict__ W1, const float* __restrict__ b1,
    const float* __restrict__ W2, const float* __restrict__ b2,
    const float* __restrict__ W3, const float* __restrict__ b3,
    const double* __restrict__ wsS,
    double* __restrict__ QHAT, double* __restrict__ SKT) {
  __shared__ double Xt[64][65];
  __shared__ float  Wl[64][65];
  __shared__ float  bsS[64];
  __shared__ float  cl[16][65];
  __shared__ double kh[64][17];
  __shared__ double Sl[256];

  const int t = threadIdx.x;
  const int blk = blockIdx.x;
  const int side = blk >> 9;
  const int idx = blk & 511;
  const int bh = idx >> 5;
  const int h = bh & 7;
  const int chunk = idx & 31;
  const size_t t0 = (size_t)bh * 2048 + (size_t)chunk * 64;

  const float* src = side ? K : Q;
  for (int i = t; i < 4096; i += 256) Xt[i >> 6][i & 63] = (double)src[t0 * 64 + i];

  const float* Ws[3] = {W1, W2, W3};
  const float* bs[3] = {b1, b2, b3};
  const int te = t & 15, tt = t >> 4;
  const int e0 = te * 4, tok0 = tt * 4;

  for (int l = 0; l < 3; ++l) {
    __syncthreads();
    for (int i = t; i < 4096; i += 256) Wl[i >> 6][i & 63] = Ws[l][i];
    if (t < 64) bsS[t] = bs[l][t];
    __syncthreads();
    double o[4][4];
#pragma unroll
    for (int i = 0; i < 4; ++i)
#pragma unroll
      for (int j = 0; j < 4; ++j) o[i][j] = 0.0;
    for (int d = 0; d < 64; ++d) {
      const double x0 = Xt[tok0 + 0][d], x1 = Xt[tok0 + 1][d], x2 = Xt[tok0 + 2][d], x3 = Xt[tok0 + 3][d];
      const double w0 = (double)Wl[e0 + 0][d], w1 = (double)Wl[e0 + 1][d];
      const double w2 = (double)Wl[e0 + 2][d], w3 = (double)Wl[e0 + 3][d];
      o[0][0] += x0 * w0; o[0][1] += x0 * w1; o[0][2] += x0 * w2; o[0][3] += x0 * w3;
      o[1][0] += x1 * w0; o[1][1] += x1 * w1; o[1][2] += x1 * w2; o[1][3] += x1 * w3;
      o[2][0] += x2 * w0; o[2][1] += x2 * w1; o[2][2] += x2 * w2; o[2][3] += x2 * w3;
      o[3][0] += x3 * w0; o[3][1] += x3 * w1; o[3][2] += x3 * w2; o[3][3] += x3 * w3;
    }
#pragma unroll
    for (int i = 0; i < 4; ++i)
#pragma unroll
      for (int j = 0; j < 4; ++j) {
        double v = o[i][j] + (double)bsS[e0 + j];
        if (l < 2) v = fmax(v, 0.0);
        o[i][j] = v;
      }
    __syncthreads();
#pragma unroll
    for (int i = 0; i < 4; ++i)
#pragma unroll
      for (int j = 0; j < 4; ++j) Xt[tok0 + i][e0 + j] = o[i][j];
  }
  __syncthreads();
  for (int i = t; i < 1024; i += 256) cl[i >> 6][i & 63] = emb[(size_t)h * 1024 + i];
  if (side) { for (int i = t; i < 256; i += 256) Sl[i] = wsS[h * 256 + i]; }
  __syncthreads();

  const int tok = t >> 2, k0 = (t & 3) * 4;
  double z[4] = {0.0, 0.0, 0.0, 0.0};
  for (int d = 0; d < 64; ++d) {
    const double xv = Xt[tok][d];
    z[0] += xv * (double)cl[k0 + 0][d]; z[1] += xv * (double)cl[k0 + 1][d];
    z[2] += xv * (double)cl[k0 + 2][d]; z[3] += xv * (double)cl[k0 + 3][d];
  }
  double hat[4];
#pragma unroll
  for (int j = 0; j < 4; ++j) hat[j] = 1.0 / (1.0 + exp(-z[j]));

  if (!side) {
#pragma unroll
    for (int j = 0; j < 4; ++j) QHAT[(t0 + tok) * 16 + k0 + j] = hat[j];
  } else {
    kh[tok][k0 + 0] = hat[0]; kh[tok][k0 + 1] = hat[1];
    kh[tok][k0 + 2] = hat[2]; kh[tok][k0 + 3] = hat[3];
    __syncthreads();
    double sk[4] = {0.0, 0.0, 0.0, 0.0};
    for (int jj = 0; jj < 16; ++jj) {
      const double kv = kh[tok][jj];
      sk[0] += Sl[(k0 + 0) * 16 + jj] * kv; sk[1] += Sl[(k0 + 1) * 16 + jj] * kv;
      sk[2] += Sl[(k0 + 2) * 16 + jj] * kv; sk[3] += Sl[(k0 + 3) * 16 + jj] * kv;
    }
#pragma unroll
    for (int j = 0; j < 4; ++j) SKT[(t0 + tok) * 16 + k0 + j] = sk[j];
  }
}

// ---------------- kSample: Bernoulli bits + graph + sparsity ----------------
__global__ __launch_bounds__(256, 4) void kSample(
    const float* __restrict__ noise,
    const double* __restrict__ qhat, const double* __restrict__ skt,
    float* __restrict__ wsSP,
    unsigned int* __restrict__ GB32, float* __restrict__ GOUT) {
  __shared__ double qhS[64][18];   // 64 rows x 16 f64 (padded, 16B-aligned rows)
  const int t = threadIdx.x;
  const int lane = t & 63, wave = t >> 6;
  const int bh = blockIdx.y, h = bh & 7;
  const int n0 = blockIdx.x * 64;

  for (int i = t; i < 1024; i += 256) qhS[i >> 4][i & 15] = qhat[((size_t)bh * 2048 + n0) * 16 + i];
  __syncthreads();

  int cnt = 0;
  for (int chunk = 0; chunk < 8; ++chunk) {
    const int m = chunk * 256 + wave * 64 + lane;
    double skv[16];
    const double* sp = skt + ((size_t)bh * 2048 + m) * 16;
#pragma unroll
    for (int q = 0; q < 8; ++q) *(f64x2*)(skv + 2 * q) = *(const f64x2*)(sp + 2 * q);
    const float* nzp = noise + ((size_t)bh * 2048 + n0) * 2048 + m;
    unsigned long long* gbp =
        (unsigned long long*)GB32 + ((size_t)bh * 2048 + n0) * 32 + chunk * 4 + wave;
    float* gop = GOUT + ((size_t)bh * 2048 + n0) * 2048 + m;

    for (int n = 0; n < 64; n += 4) {
      float nz[4];
#pragma unroll
      for (int j = 0; j < 4; ++j) nz[j] = nzp[(size_t)(n + j) * 2048];
#pragma unroll
      for (int j = 0; j < 4; ++j) {
        double ea = 0.0;
#pragma unroll
        for (int q = 0; q < 8; ++q) {
          const f64x2 qv = *(const f64x2*)&qhS[n + j][2 * q];
          ea += qv[0] * skv[2 * q];        // sequential k order (validated)
          ea += qv[1] * skv[2 * q + 1];
        }
        const int g = ((double)nz[j] < ea) ? 1 : 0;
        cnt += g;
        const unsigned long long ball = __ballot(g);
        if (lane == 0) gbp[(size_t)(n + j) * 32] = ball;
        gop[(size_t)(n + j) * 2048] = g ? 1.0f : 0.0f;
      }
    }
  }
  cnt += __shfl_xor(cnt, 1); cnt += __shfl_xor(cnt, 2); cnt += __shfl_xor(cnt, 4);
  cnt += __shfl_xor(cnt, 8); cnt += __shfl_xor(cnt, 16); cnt += __shfl_xor(cnt, 32);
  if (lane == 0) atomicAdd(&wsSP[h], (float)cnt);
}

// ---------------- kCvt: K->bf16 KB, V->bf16 transposed VT ----------------
__global__ __launch_bounds__(256) void kCvt(const float* __restrict__ K,
                                            const float* __restrict__ V,
                                            unsigned short* __restrict__ KB,
                                            unsigned short* __restrict__ VT) {
  __shared__ float vt[128][65];
  const int t = threadIdx.x;
  const int bh = blockIdx.x, ch = blockIdx.y;
  const size_t base = ((size_t)bh * 2048 + ch * 128) * 64;
  for (int i = t; i < 8192; i += 256) {
    KB[base + i] = f2bf(K[base + i]);
    vt[i >> 6][i & 63] = V[base + i];
  }
  __syncthreads();
  const size_t vbase = (size_t)bh * 64 * 2048 + ch * 128;
  for (int i = t; i < 8192; i += 256) {
    const int d = i >> 7, mm = i & 127;
    VT[vbase + (size_t)d * 2048 + mm] = f2bf(vt[mm][d]);
  }
}

// ---------------- kAttn: two-phase MFMA attention (no f64) ----------------
__global__ __launch_bounds__(256, 4) void kAttn(
    const float* __restrict__ Q, const int* __restrict__ maskp,
    const unsigned short* __restrict__ KB, const unsigned short* __restrict__ VT,
    const unsigned int* __restrict__ GB32,
    float* __restrict__ XOUT, float* __restrict__ AOUT) {
  __shared__ unsigned int bitsS[16][64];         // 4 KB
  __shared__ unsigned short stageS[4][16][32];   // 4 KB
  __shared__ float dredS[4][16];
  __shared__ float dinvS[16];
  __shared__ float xredS[16][68];                // 4.35 KB

  const int t = threadIdx.x;
  const int wave = t >> 6, lane = t & 63;
  const int bh = blockIdx.y, b = bh >> 3;
  const int n0 = blockIdx.x * 16;
  const int hi2 = lane >> 4;
  const int hi8 = hi2 << 3;
  const int g4 = hi2 << 2;
  const int lm = lane & 15;

  for (int i = t; i < 1024; i += 256)
    bitsS[i >> 6][i & 63] = GB32[((size_t)bh * 2048 + n0 + (i >> 6)) * 64 + (i & 63)];
  for (int i = t; i < 16 * 68; i += 256) ((float*)xredS)[i] = 0.f;

  // Q A-fragments (f32 -> bf16)
  const float* qrow = Q + ((size_t)bh * 2048 + n0 + lm) * 64;
  bf16x8 aq[2];
#pragma unroll
  for (int hh = 0; hh < 2; ++hh) {
    const int d0 = hi8 + hh * 32;
    const f32x4 qa = *(const f32x4*)(qrow + d0);
    const f32x4 qb = *(const f32x4*)(qrow + d0 + 4);
    bf16x8 v;
    v[0] = (__bf16)qa[0]; v[1] = (__bf16)qa[1]; v[2] = (__bf16)qa[2]; v[3] = (__bf16)qa[3];
    v[4] = (__bf16)qb[0]; v[5] = (__bf16)qb[1]; v[6] = (__bf16)qb[2]; v[7] = (__bf16)qb[3];
    aq[hh] = v;
  }

  const unsigned short* kbp = KB + (size_t)bh * 2048 * 64;
  const unsigned short* vtp = VT + (size_t)bh * 64 * 2048;
  const int* mkp = maskp + b * 2048;
  __syncthreads();

  // ======== PHASE 1: denominators ========
  float dsum[4] = {0.f, 0.f, 0.f, 0.f};
  for (int it = 0; it < 16; ++it) {
    const int mb = ((it << 2) + wave) << 5;
    f32x4 st[2];
#pragma unroll
    for (int tt = 0; tt < 2; ++tt) {
      const unsigned short* kr = kbp + (size_t)(mb + tt * 16 + lm) * 64 + hi8;
      const bf16x8 b0 = *(const bf16x8*)(kr);
      const bf16x8 b1 = *(const bf16x8*)(kr + 32);
      f32x4 acc = (f32x4){0.f, 0.f, 0.f, 0.f};
      acc = __builtin_amdgcn_mfma_f32_16x16x32_bf16(aq[0], b0, acc, 0, 0, 0);
      acc = __builtin_amdgcn_mfma_f32_16x16x32_bf16(aq[1], b1, acc, 0, 0, 0);
      st[tt] = acc;
    }
#pragma unroll
    for (int tt = 0; tt < 2; ++tt) {
      const int mv = mkp[mb + tt * 16 + lm];
      const f32x4 sv4 = st[tt];
#pragma unroll
      for (int r = 0; r < 4; ++r) {
        const int g = (bitsS[g4 + r][mb >> 5] >> (tt * 16 + lm)) & 1;
        if (g && !mv) dsum[r] += __expf(sv4[r] * 0.125f);
      }
    }
  }
#pragma unroll
  for (int r = 0; r < 4; ++r) {
    float v = dsum[r];
    v += __shfl_xor(v, 1); v += __shfl_xor(v, 2); v += __shfl_xor(v, 4); v += __shfl_xor(v, 8);
    if (lm == 0) dredS[wave][g4 + r] = v;
  }
  __syncthreads();
  if (t < 16) {
    const float dv = dredS[0][t] + dredS[1][t] + dredS[2][t] + dredS[3][t];
    dinvS[t] = 1.0f / fmaxf(dv, 1e-12f);
  }
  __syncthreads();

  // ======== PHASE 2: u rebuild, PV, attn writes ========
  const size_t rowbase = (size_t)bh * 2048 + n0;
  f32x4 xacc[4];
#pragma unroll
  for (int td = 0; td < 4; ++td) xacc[td] = (f32x4){0.f, 0.f, 0.f, 0.f};

  for (int it = 0; it < 16; ++it) {
    const int mb = ((it << 2) + wave) << 5;
    f32x4 st[2];
#pragma unroll
    for (int tt = 0; tt < 2; ++tt) {
      const unsigned short* kr = kbp + (size_t)(mb + tt * 16 + lm) * 64 + hi8;
      const bf16x8 b0 = *(const bf16x8*)(kr);
      const bf16x8 b1 = *(const bf16x8*)(kr + 32);
      f32x4 acc = (f32x4){0.f, 0.f, 0.f, 0.f};
      acc = __builtin_amdgcn_mfma_f32_16x16x32_bf16(aq[0], b0, acc, 0, 0, 0);
      acc = __builtin_amdgcn_mfma_f32_16x16x32_bf16(aq[1], b1, acc, 0, 0, 0);
      st[tt] = acc;
    }
#pragma unroll
    for (int tt = 0; tt < 2; ++tt) {
      const int mv = mkp[mb + tt * 16 + lm];
      const f32x4 sv4 = st[tt];
#pragma unroll
      for (int r = 0; r < 4; ++r) {
        const int row = g4 + r;
        const int g = (bitsS[row][mb >> 5] >> (tt * 16 + lm)) & 1;
        const float u = (g && !mv) ? __expf(sv4[r] * 0.125f) : 0.f;
        const int col = tt * 16 + lm;
        stageS[wave][row][col ^ (((row >> 2) & 3) << 3)] = f2bf(u);
      }
    }
    // PV MFMA from staged A-fragments
    {
      const int rdcol = hi8 ^ (((lm >> 2) & 3) << 3);
      const bf16x8 ua = *(const bf16x8*)&stageS[wave][lm][rdcol];
#pragma unroll
      for (int td = 0; td < 4; ++td) {
        const bf16x8 vb = *(const bf16x8*)(vtp + (size_t)(td * 16 + lm) * 2048 + mb + hi8);
        xacc[td] = __builtin_amdgcn_mfma_f32_16x16x32_bf16(ua, vb, xacc[td], 0, 0, 0);
      }
    }
    // coalesced attn write for this 16x32 block
    {
      const int row = lane >> 2, q = lane & 3;
      const int rc = (q * 8) ^ (((row >> 2) & 3) << 3);
      const unsigned short* up = &stageS[wave][row][rc];
      const float inv = dinvS[row];
      f32x8 av;
#pragma unroll
      for (int j = 0; j < 8; ++j) av[j] = (float)__builtin_bit_cast(__bf16, up[j]) * inv;
      *(f32x8*)(AOUT + (rowbase + row) * 2048 + mb + q * 8) = av;
    }
  }

  // ---- X cross-wave reduce + write ----
  for (int w = 0; w < 4; ++w) {
    if (wave == w) {
#pragma unroll
      for (int td = 0; td < 4; ++td)
#pragma unroll
        for (int r = 0; r < 4; ++r) xredS[g4 + r][td * 16 + lm] += xacc[td][r];
    }
    __syncthreads();
  }
  for (int i = t; i < 1024; i += 256) {
    const int nl = i >> 6, d = i & 63;
    XOUT[(rowbase + nl) * 64 + d] = xredS[nl][d] * dinvS[nl];
  }
}

// ---------------- kFin: sparsity (f32) ----------------
__global__ void kFin(const float* __restrict__ wsSP, float* __restrict__ SPOUT) {
  const int t = threadIdx.x;
  if (t < 8) SPOUT[t] = wsSP[t] * (1.0f / 8388608.0f);  // /(2*2048*2048)
}

extern "C" void kernel_launch(void* const* d_in, const int* in_sizes, int n_in,
                              void* d_out, int out_size, void* d_ws, size_t ws_size,
                              hipStream_t stream) {
  const float* Q = (const float*)d_in[0];
  const float* K = (const float*)d_in[1];
  const float* V = (const float*)d_in[2];
  const int* mask = (const int*)d_in[3];
  const float* noise = (const float*)d_in[4];
  const float* emb = (const float*)d_in[5];
  const float* W1 = (const float*)d_in[6];
  const float* b1 = (const float*)d_in[7];
  const float* W2 = (const float*)d_in[8];
  const float* b2 = (const float*)d_in[9];
  const float* W3 = (const float*)d_in[10];
  const float* b3 = (const float*)d_in[11];

  char* ws = (char*)d_ws;
  double* wsS = (double*)(ws + 0);                          // 16 KB
  float* wsSP = (float*)(ws + 16384);                       // 8 f32
  double* QHAT = (double*)(ws + 32768);                     // 4 MB f64
  double* SKT  = (double*)(ws + 32768 + 4194304);           // 4 MB f64
  // aliases (live only after kSample):
  unsigned short* KB = (unsigned short*)(ws + 32768);             // 4 MB bf16
  unsigned short* VT = (unsigned short*)(ws + 32768 + 4194304);   // 4 MB bf16
  unsigned int* GB32 = (unsigned int*)(ws + 32768 + 8388608);     // 8 MB bits

  float* out = (float*)d_out;                     // FLOAT32 outputs
  float* XOUT = out;                              // 2*8*2048*64
  float* SPOUT = out + 2097152;                   // 8
  float* GOUT = out + 2097160;                    // 2*8*2048*2048
  float* AOUT = out + 69206024;                   // 2*8*2048*2048

  kS<<<8, 256, 0, stream>>>(emb, wsS, wsSP);
  kMLP<<<1024, 256, 0, stream>>>(Q, K, emb, W1, b1, W2, b2, W3, b3, wsS, QHAT, SKT);
  kSample<<<dim3(32, 16), 256, 0, stream>>>(noise, QHAT, SKT, wsSP, GB32, GOUT);
  kCvt<<<dim3(16, 16), 256, 0, stream>>>(K, V, KB, VT);   // overwrites QHAT/SKT
  kAttn<<<dim3(128, 16), 256, 0, stream>>>(Q, mask, KB, VT, GB32, XOUT, AOUT);
  kFin<<<1, 64, 0, stream>>>(wsSP, SPOUT);
}

// Round 9
// 522.546 us; speedup vs baseline: 4.0298x; 1.0591x over previous
//
#include <hip/hip_runtime.h>

// SBMAttention — round 9: kSample without LDS broadcast reads.
// r8: 553 µs total; model says kSample was LDS-issue-bound (8 ds_read_b128
// per wave-sample for the wave-uniform qhat row ≈ 160 µs of serialization).
// Fix: read the qhat row from global with wave-uniform addresses (scalar
// s_load path), delete the LDS staging + syncthreads, double the grid.
// Everything else (kS/kMLP/kCvt/kAttn/kFin, ws aliasing) unchanged from the
// validated r8 structure. f64 sequential-k sampling order preserved exactly.

typedef float  f32x4 __attribute__((ext_vector_type(4)));
typedef float  f32x8 __attribute__((ext_vector_type(8)));
typedef double f64x2 __attribute__((ext_vector_type(2)));
typedef __bf16 bf16x8 __attribute__((ext_vector_type(8)));

__device__ __forceinline__ unsigned short f2bf(float f) {
  __bf16 b = (__bf16)f;
  return __builtin_bit_cast(unsigned short, b);
}

// ---------------- kS: cluster softmax (f64) — validated ----------------
__global__ __launch_bounds__(256) void kS(const float* __restrict__ emb,
                                          double* __restrict__ wsS,
                                          float* __restrict__ wsSP) {
  __shared__ double c[16][65];
  __shared__ double red[256];
  const int t = threadIdx.x, h = blockIdx.x;
  if (t == 0) wsSP[h] = 0.f;
  for (int i = t; i < 1024; i += 256) c[i >> 6][i & 63] = (double)emb[(size_t)h * 1024 + i];
  __syncthreads();
  const int k = t >> 4, j = t & 15;
  double acc = 0.0;
  for (int d = 0; d < 64; ++d) acc += c[k][d] * c[j][d];
  red[t] = acc; __syncthreads();
  for (int s = 128; s > 0; s >>= 1) { if (t < s) red[t] = fmax(red[t], red[t + s]); __syncthreads(); }
  const double mx = red[0]; __syncthreads();
  const double e = exp(acc - mx);
  red[t] = e; __syncthreads();
  for (int s = 128; s > 0; s >>= 1) { if (t < s) red[t] += red[t + s]; __syncthreads(); }
  wsS[h * 256 + t] = e / red[0];
}

// ---------------- kMLP: proj + hats (f64) — validated ----------------
__global__ __launch_bounds__(256) void kMLP(
    const float* __restrict__ Q, const float* __restrict__ K,
    const float* __restrict__ emb,
    const float* __restrict__ W1, const float* __restrict__ b1,
    const float* __restrict__ W2, const float* __restrict__ b2,
    const float* __restrict__ W3, const float* __restrict__ b3,
    const double* __restrict__ wsS,
    double* __restrict__ QHAT, double* __restrict__ SKT) {
  __shared__ double Xt[64][65];
  __shared__ float  Wl[64][65];
  __shared__ float  bsS[64];
  __shared__ float  cl[16][65];
  __shared__ double kh[64][17];
  __shared__ double Sl[256];

  const int t = threadIdx.x;
  const int blk = blockIdx.x;
  const int side = blk >> 9;
  const int idx = blk & 511;
  const int bh = idx >> 5;
  const int h = bh & 7;
  const int chunk = idx & 31;
  const size_t t0 = (size_t)bh * 2048 + (size_t)chunk * 64;

  const float* src = side ? K : Q;
  for (int i = t; i < 4096; i += 256) Xt[i >> 6][i & 63] = (double)src[t0 * 64 + i];

  const float* Ws[3] = {W1, W2, W3};
  const float* bs[3] = {b1, b2, b3};
  const int te = t & 15, tt = t >> 4;
  const int e0 = te * 4, tok0 = tt * 4;

  for (int l = 0; l < 3; ++l) {
    __syncthreads();
    for (int i = t; i < 4096; i += 256) Wl[i >> 6][i & 63] = Ws[l][i];
    if (t < 64) bsS[t] = bs[l][t];
    __syncthreads();
    double o[4][4];
#pragma unroll
    for (int i = 0; i < 4; ++i)
#pragma unroll
      for (int j = 0; j < 4; ++j) o[i][j] = 0.0;
    for (int d = 0; d < 64; ++d) {
      const double x0 = Xt[tok0 + 0][d], x1 = Xt[tok0 + 1][d], x2 = Xt[tok0 + 2][d], x3 = Xt[tok0 + 3][d];
      const double w0 = (double)Wl[e0 + 0][d], w1 = (double)Wl[e0 + 1][d];
      const double w2 = (double)Wl[e0 + 2][d], w3 = (double)Wl[e0 + 3][d];
      o[0][0] += x0 * w0; o[0][1] += x0 * w1; o[0][2] += x0 * w2; o[0][3] += x0 * w3;
      o[1][0] += x1 * w0; o[1][1] += x1 * w1; o[1][2] += x1 * w2; o[1][3] += x1 * w3;
      o[2][0] += x2 * w0; o[2][1] += x2 * w1; o[2][2] += x2 * w2; o[2][3] += x2 * w3;
      o[3][0] += x3 * w0; o[3][1] += x3 * w1; o[3][2] += x3 * w2; o[3][3] += x3 * w3;
    }
#pragma unroll
    for (int i = 0; i < 4; ++i)
#pragma unroll
      for (int j = 0; j < 4; ++j) {
        double v = o[i][j] + (double)bsS[e0 + j];
        if (l < 2) v = fmax(v, 0.0);
        o[i][j] = v;
      }
    __syncthreads();
#pragma unroll
    for (int i = 0; i < 4; ++i)
#pragma unroll
      for (int j = 0; j < 4; ++j) Xt[tok0 + i][e0 + j] = o[i][j];
  }
  __syncthreads();
  for (int i = t; i < 1024; i += 256) cl[i >> 6][i & 63] = emb[(size_t)h * 1024 + i];
  if (side) { for (int i = t; i < 256; i += 256) Sl[i] = wsS[h * 256 + i]; }
  __syncthreads();

  const int tok = t >> 2, k0 = (t & 3) * 4;
  double z[4] = {0.0, 0.0, 0.0, 0.0};
  for (int d = 0; d < 64; ++d) {
    const double xv = Xt[tok][d];
    z[0] += xv * (double)cl[k0 + 0][d]; z[1] += xv * (double)cl[k0 + 1][d];
    z[2] += xv * (double)cl[k0 + 2][d]; z[3] += xv * (double)cl[k0 + 3][d];
  }
  double hat[4];
#pragma unroll
  for (int j = 0; j < 4; ++j) hat[j] = 1.0 / (1.0 + exp(-z[j]));

  if (!side) {
#pragma unroll
    for (int j = 0; j < 4; ++j) QHAT[(t0 + tok) * 16 + k0 + j] = hat[j];
  } else {
    kh[tok][k0 + 0] = hat[0]; kh[tok][k0 + 1] = hat[1];
    kh[tok][k0 + 2] = hat[2]; kh[tok][k0 + 3] = hat[3];
    __syncthreads();
    double sk[4] = {0.0, 0.0, 0.0, 0.0};
    for (int jj = 0; jj < 16; ++jj) {
      const double kv = kh[tok][jj];
      sk[0] += Sl[(k0 + 0) * 16 + jj] * kv; sk[1] += Sl[(k0 + 1) * 16 + jj] * kv;
      sk[2] += Sl[(k0 + 2) * 16 + jj] * kv; sk[3] += Sl[(k0 + 3) * 16 + jj] * kv;
    }
#pragma unroll
    for (int j = 0; j < 4; ++j) SKT[(t0 + tok) * 16 + k0 + j] = sk[j];
  }
}

// ---------------- kSample: bits + graph + sparsity (no LDS) ----------------
__global__ __launch_bounds__(256, 4) void kSample(
    const float* __restrict__ noise,
    const double* __restrict__ qhat, const double* __restrict__ skt,
    float* __restrict__ wsSP,
    unsigned long long* __restrict__ GB64, float* __restrict__ GOUT) {
  const int t = threadIdx.x;
  const int lane = t & 63, wave = t >> 6;
  const int bh = blockIdx.y, h = bh & 7;
  const int n0 = blockIdx.x * 32;

  int cnt = 0;
  for (int chunk = 0; chunk < 8; ++chunk) {
    const int m = chunk * 256 + wave * 64 + lane;
    double skv[16];
    const double* sp = skt + ((size_t)bh * 2048 + m) * 16;
#pragma unroll
    for (int q = 0; q < 8; ++q) *(f64x2*)(skv + 2 * q) = *(const f64x2*)(sp + 2 * q);
    const float* nzp = noise + ((size_t)bh * 2048 + n0) * 2048 + m;
    unsigned long long* gbp = GB64 + ((size_t)bh * 2048 + n0) * 32 + chunk * 4 + wave;
    float* gop = GOUT + ((size_t)bh * 2048 + n0) * 2048 + m;
    const double* qbase = qhat + ((size_t)bh * 2048 + n0) * 16;  // wave-uniform

    for (int n = 0; n < 32; n += 2) {
      const float nz0 = nzp[(size_t)n * 2048];
      const float nz1 = nzp[(size_t)(n + 1) * 2048];
      const double* q0 = qbase + (size_t)n * 16;       // uniform -> s_load
      const double* q1 = qbase + (size_t)(n + 1) * 16;
      double ea0 = 0.0, ea1 = 0.0;
#pragma unroll
      for (int k = 0; k < 16; ++k) {                   // sequential k (validated)
        ea0 += q0[k] * skv[k];
        ea1 += q1[k] * skv[k];
      }
      const int g0 = ((double)nz0 < ea0) ? 1 : 0;
      const int g1 = ((double)nz1 < ea1) ? 1 : 0;
      cnt += g0 + g1;
      const unsigned long long b0 = __ballot(g0);
      const unsigned long long b1 = __ballot(g1);
      if (lane == 0) {
        gbp[(size_t)n * 32] = b0;
        gbp[(size_t)(n + 1) * 32] = b1;
      }
      gop[(size_t)n * 2048] = g0 ? 1.0f : 0.0f;
      gop[(size_t)(n + 1) * 2048] = g1 ? 1.0f : 0.0f;
    }
  }
  cnt += __shfl_xor(cnt, 1); cnt += __shfl_xor(cnt, 2); cnt += __shfl_xor(cnt, 4);
  cnt += __shfl_xor(cnt, 8); cnt += __shfl_xor(cnt, 16); cnt += __shfl_xor(cnt, 32);
  if (lane == 0) atomicAdd(&wsSP[h], (float)cnt);
}

// ---------------- kCvt: K->bf16 KB, V->bf16 transposed VT ----------------
__global__ __launch_bounds__(256) void kCvt(const float* __restrict__ K,
                                            const float* __restrict__ V,
                                            unsigned short* __restrict__ KB,
                                            unsigned short* __restrict__ VT) {
  __shared__ float vt[128][65];
  const int t = threadIdx.x;
  const int bh = blockIdx.x, ch = blockIdx.y;
  const size_t base = ((size_t)bh * 2048 + ch * 128) * 64;
  for (int i = t; i < 8192; i += 256) {
    KB[base + i] = f2bf(K[base + i]);
    vt[i >> 6][i & 63] = V[base + i];
  }
  __syncthreads();
  const size_t vbase = (size_t)bh * 64 * 2048 + ch * 128;
  for (int i = t; i < 8192; i += 256) {
    const int d = i >> 7, mm = i & 127;
    VT[vbase + (size_t)d * 2048 + mm] = f2bf(vt[mm][d]);
  }
}

// ---------------- kAttn: two-phase MFMA attention (no f64) ----------------
__global__ __launch_bounds__(256, 4) void kAttn(
    const float* __restrict__ Q, const int* __restrict__ maskp,
    const unsigned short* __restrict__ KB, const unsigned short* __restrict__ VT,
    const unsigned int* __restrict__ GB32,
    float* __restrict__ XOUT, float* __restrict__ AOUT) {
  __shared__ unsigned int bitsS[16][64];         // 4 KB
  __shared__ unsigned short stageS[4][16][32];   // 4 KB
  __shared__ float dredS[4][16];
  __shared__ float dinvS[16];
  __shared__ float xredS[16][68];                // 4.35 KB

  const int t = threadIdx.x;
  const int wave = t >> 6, lane = t & 63;
  const int bh = blockIdx.y, b = bh >> 3;
  const int n0 = blockIdx.x * 16;
  const int hi2 = lane >> 4;
  const int hi8 = hi2 << 3;
  const int g4 = hi2 << 2;
  const int lm = lane & 15;

  for (int i = t; i < 1024; i += 256)
    bitsS[i >> 6][i & 63] = GB32[((size_t)bh * 2048 + n0 + (i >> 6)) * 64 + (i & 63)];
  for (int i = t; i < 16 * 68; i += 256) ((float*)xredS)[i] = 0.f;

  // Q A-fragments (f32 -> bf16)
  const float* qrow = Q + ((size_t)bh * 2048 + n0 + lm) * 64;
  bf16x8 aq[2];
#pragma unroll
  for (int hh = 0; hh < 2; ++hh) {
    const int d0 = hi8 + hh * 32;
    const f32x4 qa = *(const f32x4*)(qrow + d0);
    const f32x4 qb = *(const f32x4*)(qrow + d0 + 4);
    bf16x8 v;
    v[0] = (__bf16)qa[0]; v[1] = (__bf16)qa[1]; v[2] = (__bf16)qa[2]; v[3] = (__bf16)qa[3];
    v[4] = (__bf16)qb[0]; v[5] = (__bf16)qb[1]; v[6] = (__bf16)qb[2]; v[7] = (__bf16)qb[3];
    aq[hh] = v;
  }

  const unsigned short* kbp = KB + (size_t)bh * 2048 * 64;
  const unsigned short* vtp = VT + (size_t)bh * 64 * 2048;
  const int* mkp = maskp + b * 2048;
  __syncthreads();

  // ======== PHASE 1: denominators ========
  float dsum[4] = {0.f, 0.f, 0.f, 0.f};
  for (int it = 0; it < 16; ++it) {
    const int mb = ((it << 2) + wave) << 5;
    f32x4 st[2];
#pragma unroll
    for (int tt = 0; tt < 2; ++tt) {
      const unsigned short* kr = kbp + (size_t)(mb + tt * 16 + lm) * 64 + hi8;
      const bf16x8 b0 = *(const bf16x8*)(kr);
      const bf16x8 b1 = *(const bf16x8*)(kr + 32);
      f32x4 acc = (f32x4){0.f, 0.f, 0.f, 0.f};
      acc = __builtin_amdgcn_mfma_f32_16x16x32_bf16(aq[0], b0, acc, 0, 0, 0);
      acc = __builtin_amdgcn_mfma_f32_16x16x32_bf16(aq[1], b1, acc, 0, 0, 0);
      st[tt] = acc;
    }
#pragma unroll
    for (int tt = 0; tt < 2; ++tt) {
      const int mv = mkp[mb + tt * 16 + lm];
      const f32x4 sv4 = st[tt];
#pragma unroll
      for (int r = 0; r < 4; ++r) {
        const int g = (bitsS[g4 + r][mb >> 5] >> (tt * 16 + lm)) & 1;
        if (g && !mv) dsum[r] += __expf(sv4[r] * 0.125f);
      }
    }
  }
#pragma unroll
  for (int r = 0; r < 4; ++r) {
    float v = dsum[r];
    v += __shfl_xor(v, 1); v += __shfl_xor(v, 2); v += __shfl_xor(v, 4); v += __shfl_xor(v, 8);
    if (lm == 0) dredS[wave][g4 + r] = v;
  }
  __syncthreads();
  if (t < 16) {
    const float dv = dredS[0][t] + dredS[1][t] + dredS[2][t] + dredS[3][t];
    dinvS[t] = 1.0f / fmaxf(dv, 1e-12f);
  }
  __syncthreads();

  // ======== PHASE 2: u rebuild, PV, attn writes ========
  const size_t rowbase = (size_t)bh * 2048 + n0;
  f32x4 xacc[4];
#pragma unroll
  for (int td = 0; td < 4; ++td) xacc[td] = (f32x4){0.f, 0.f, 0.f, 0.f};

  for (int it = 0; it < 16; ++it) {
    const int mb = ((it << 2) + wave) << 5;
    f32x4 st[2];
#pragma unroll
    for (int tt = 0; tt < 2; ++tt) {
      const unsigned short* kr = kbp + (size_t)(mb + tt * 16 + lm) * 64 + hi8;
      const bf16x8 b0 = *(const bf16x8*)(kr);
      const bf16x8 b1 = *(const bf16x8*)(kr + 32);
      f32x4 acc = (f32x4){0.f, 0.f, 0.f, 0.f};
      acc = __builtin_amdgcn_mfma_f32_16x16x32_bf16(aq[0], b0, acc, 0, 0, 0);
      acc = __builtin_amdgcn_mfma_f32_16x16x32_bf16(aq[1], b1, acc, 0, 0, 0);
      st[tt] = acc;
    }
#pragma unroll
    for (int tt = 0; tt < 2; ++tt) {
      const int mv = mkp[mb + tt * 16 + lm];
      const f32x4 sv4 = st[tt];
#pragma unroll
      for (int r = 0; r < 4; ++r) {
        const int row = g4 + r;
        const int g = (bitsS[row][mb >> 5] >> (tt * 16 + lm)) & 1;
        const float u = (g && !mv) ? __expf(sv4[r] * 0.125f) : 0.f;
        const int col = tt * 16 + lm;
        stageS[wave][row][col ^ (((row >> 2) & 3) << 3)] = f2bf(u);
      }
    }
    // PV MFMA from staged A-fragments
    {
      const int rdcol = hi8 ^ (((lm >> 2) & 3) << 3);
      const bf16x8 ua = *(const bf16x8*)&stageS[wave][lm][rdcol];
#pragma unroll
      for (int td = 0; td < 4; ++td) {
        const bf16x8 vb = *(const bf16x8*)(vtp + (size_t)(td * 16 + lm) * 2048 + mb + hi8);
        xacc[td] = __builtin_amdgcn_mfma_f32_16x16x32_bf16(ua, vb, xacc[td], 0, 0, 0);
      }
    }
    // coalesced attn write for this 16x32 block
    {
      const int row = lane >> 2, q = lane & 3;
      const int rc = (q * 8) ^ (((row >> 2) & 3) << 3);
      const unsigned short* up = &stageS[wave][row][rc];
      const float inv = dinvS[row];
      f32x8 av;
#pragma unroll
      for (int j = 0; j < 8; ++j) av[j] = (float)__builtin_bit_cast(__bf16, up[j]) * inv;
      *(f32x8*)(AOUT + (rowbase + row) * 2048 + mb + q * 8) = av;
    }
  }

  // ---- X cross-wave reduce + write ----
  for (int w = 0; w < 4; ++w) {
    if (wave == w) {
#pragma unroll
      for (int td = 0; td < 4; ++td)
#pragma unroll
        for (int r = 0; r < 4; ++r) xredS[g4 + r][td * 16 + lm] += xacc[td][r];
    }
    __syncthreads();
  }
  for (int i = t; i < 1024; i += 256) {
    const int nl = i >> 6, d = i & 63;
    XOUT[(rowbase + nl) * 64 + d] = xredS[nl][d] * dinvS[nl];
  }
}

// ---------------- kFin: sparsity (f32) ----------------
__global__ void kFin(const float* __restrict__ wsSP, float* __restrict__ SPOUT) {
  const int t = threadIdx.x;
  if (t < 8) SPOUT[t] = wsSP[t] * (1.0f / 8388608.0f);  // /(2*2048*2048)
}

extern "C" void kernel_launch(void* const* d_in, const int* in_sizes, int n_in,
                              void* d_out, int out_size, void* d_ws, size_t ws_size,
                              hipStream_t stream) {
  const float* Q = (const float*)d_in[0];
  const float* K = (const float*)d_in[1];
  const float* V = (const float*)d_in[2];
  const int* mask = (const int*)d_in[3];
  const float* noise = (const float*)d_in[4];
  const float* emb = (const float*)d_in[5];
  const float* W1 = (const float*)d_in[6];
  const float* b1 = (const float*)d_in[7];
  const float* W2 = (const float*)d_in[8];
  const float* b2 = (const float*)d_in[9];
  const float* W3 = (const float*)d_in[10];
  const float* b3 = (const float*)d_in[11];

  char* ws = (char*)d_ws;
  double* wsS = (double*)(ws + 0);                          // 16 KB
  float* wsSP = (float*)(ws + 16384);                       // 8 f32
  double* QHAT = (double*)(ws + 32768);                     // 4 MB f64
  double* SKT  = (double*)(ws + 32768 + 4194304);           // 4 MB f64
  // aliases (live only after kSample):
  unsigned short* KB = (unsigned short*)(ws + 32768);             // 4 MB bf16
  unsigned short* VT = (unsigned short*)(ws + 32768 + 4194304);   // 4 MB bf16
  unsigned long long* GB64 = (unsigned long long*)(ws + 32768 + 8388608);  // 8 MB bits
  unsigned int* GB32 = (unsigned int*)(ws + 32768 + 8388608);

  float* out = (float*)d_out;                     // FLOAT32 outputs
  float* XOUT = out;                              // 2*8*2048*64
  float* SPOUT = out + 2097152;                   // 8
  float* GOUT = out + 2097160;                    // 2*8*2048*2048
  float* AOUT = out + 69206024;                   // 2*8*2048*2048

  kS<<<8, 256, 0, stream>>>(emb, wsS, wsSP);
  kMLP<<<1024, 256, 0, stream>>>(Q, K, emb, W1, b1, W2, b2, W3, b3, wsS, QHAT, SKT);
  kSample<<<dim3(64, 16), 256, 0, stream>>>(noise, QHAT, SKT, wsSP, GB64, GOUT);
  kCvt<<<dim3(16, 16), 256, 0, stream>>>(K, V, KB, VT);   // overwrites QHAT/SKT
  kAttn<<<dim3(128, 16), 256, 0, stream>>>(Q, mask, KB, VT, GB32, XOUT, AOUT);
  kFin<<<1, 64, 0, stream>>>(wsSP, SPOUT);
}

// Round 10
// 512.131 us; speedup vs baseline: 4.1117x; 1.0203x over previous
//
#include <hip/hip_runtime.h>

// SBMAttention — round 10: contiguous HBM streams.
// r9 gap analysis: kSample walked noise/graph in 256B chunks at 8KB stride
// (column-walk) -> DRAM-row thrash -> ~2-3 TB/s effective. This round:
//  kSample: 64n x 512m tiles; thread holds 2 skt rows (32 f64) in regs across
//           all 64 rows; noise read / graph write contiguous per row.
//           Sequential-k f64 dot preserved => bit-identical sampling.
//  kAttn:   wave owns contiguous 512-col span (mb = wave*512 + it*32) so attn
//           writes append sequentially; K/VT locality improves. Bit layout
//           unchanged; denominator add-order change is f32-tolerant.
// Everything else (kS/kMLP/kCvt/kFin, ws aliasing, f32 outputs) unchanged.

typedef float  f32x4 __attribute__((ext_vector_type(4)));
typedef float  f32x8 __attribute__((ext_vector_type(8)));
typedef double f64x2 __attribute__((ext_vector_type(2)));
typedef __bf16 bf16x8 __attribute__((ext_vector_type(8)));

__device__ __forceinline__ unsigned short f2bf(float f) {
  __bf16 b = (__bf16)f;
  return __builtin_bit_cast(unsigned short, b);
}

// ---------------- kS: cluster softmax (f64) — validated ----------------
__global__ __launch_bounds__(256) void kS(const float* __restrict__ emb,
                                          double* __restrict__ wsS,
                                          float* __restrict__ wsSP) {
  __shared__ double c[16][65];
  __shared__ double red[256];
  const int t = threadIdx.x, h = blockIdx.x;
  if (t == 0) wsSP[h] = 0.f;
  for (int i = t; i < 1024; i += 256) c[i >> 6][i & 63] = (double)emb[(size_t)h * 1024 + i];
  __syncthreads();
  const int k = t >> 4, j = t & 15;
  double acc = 0.0;
  for (int d = 0; d < 64; ++d) acc += c[k][d] * c[j][d];
  red[t] = acc; __syncthreads();
  for (int s = 128; s > 0; s >>= 1) { if (t < s) red[t] = fmax(red[t], red[t + s]); __syncthreads(); }
  const double mx = red[0]; __syncthreads();
  const double e = exp(acc - mx);
  red[t] = e; __syncthreads();
  for (int s = 128; s > 0; s >>= 1) { if (t < s) red[t] += red[t + s]; __syncthreads(); }
  wsS[h * 256 + t] = e / red[0];
}

// ---------------- kMLP: proj + hats (f64) — validated ----------------
__global__ __launch_bounds__(256) void kMLP(
    const float* __restrict__ Q, const float* __restrict__ K,
    const float* __restrict__ emb,
    const float* __restrict__ W1, const float* __restrict__ b1,
    const float* __restrict__ W2, const float* __restrict__ b2,
    const float* __restrict__ W3, const float* __restrict__ b3,
    const double* __restrict__ wsS,
    double* __restrict__ QHAT, double* __restrict__ SKT) {
  __shared__ double Xt[64][65];
  __shared__ float  Wl[64][65];
  __shared__ float  bsS[64];
  __shared__ float  cl[16][65];
  __shared__ double kh[64][17];
  __shared__ double Sl[256];

  const int t = threadIdx.x;
  const int blk = blockIdx.x;
  const int side = blk >> 9;
  const int idx = blk & 511;
  const int bh = idx >> 5;
  const int h = bh & 7;
  const int chunk = idx & 31;
  const size_t t0 = (size_t)bh * 2048 + (size_t)chunk * 64;

  const float* src = side ? K : Q;
  for (int i = t; i < 4096; i += 256) Xt[i >> 6][i & 63] = (double)src[t0 * 64 + i];

  const float* Ws[3] = {W1, W2, W3};
  const float* bs[3] = {b1, b2, b3};
  const int te = t & 15, tt = t >> 4;
  const int e0 = te * 4, tok0 = tt * 4;

  for (int l = 0; l < 3; ++l) {
    __syncthreads();
    for (int i = t; i < 4096; i += 256) Wl[i >> 6][i & 63] = Ws[l][i];
    if (t < 64) bsS[t] = bs[l][t];
    __syncthreads();
    double o[4][4];
#pragma unroll
    for (int i = 0; i < 4; ++i)
#pragma unroll
      for (int j = 0; j < 4; ++j) o[i][j] = 0.0;
    for (int d = 0; d < 64; ++d) {
      const double x0 = Xt[tok0 + 0][d], x1 = Xt[tok0 + 1][d], x2 = Xt[tok0 + 2][d], x3 = Xt[tok0 + 3][d];
      const double w0 = (double)Wl[e0 + 0][d], w1 = (double)Wl[e0 + 1][d];
      const double w2 = (double)Wl[e0 + 2][d], w3 = (double)Wl[e0 + 3][d];
      o[0][0] += x0 * w0; o[0][1] += x0 * w1; o[0][2] += x0 * w2; o[0][3] += x0 * w3;
      o[1][0] += x1 * w0; o[1][1] += x1 * w1; o[1][2] += x1 * w2; o[1][3] += x1 * w3;
      o[2][0] += x2 * w0; o[2][1] += x2 * w1; o[2][2] += x2 * w2; o[2][3] += x2 * w3;
      o[3][0] += x3 * w0; o[3][1] += x3 * w1; o[3][2] += x3 * w2; o[3][3] += x3 * w3;
    }
#pragma unroll
    for (int i = 0; i < 4; ++i)
#pragma unroll
      for (int j = 0; j < 4; ++j) {
        double v = o[i][j] + (double)bsS[e0 + j];
        if (l < 2) v = fmax(v, 0.0);
        o[i][j] = v;
      }
    __syncthreads();
#pragma unroll
    for (int i = 0; i < 4; ++i)
#pragma unroll
      for (int j = 0; j < 4; ++j) Xt[tok0 + i][e0 + j] = o[i][j];
  }
  __syncthreads();
  for (int i = t; i < 1024; i += 256) cl[i >> 6][i & 63] = emb[(size_t)h * 1024 + i];
  if (side) { for (int i = t; i < 256; i += 256) Sl[i] = wsS[h * 256 + i]; }
  __syncthreads();

  const int tok = t >> 2, k0 = (t & 3) * 4;
  double z[4] = {0.0, 0.0, 0.0, 0.0};
  for (int d = 0; d < 64; ++d) {
    const double xv = Xt[tok][d];
    z[0] += xv * (double)cl[k0 + 0][d]; z[1] += xv * (double)cl[k0 + 1][d];
    z[2] += xv * (double)cl[k0 + 2][d]; z[3] += xv * (double)cl[k0 + 3][d];
  }
  double hat[4];
#pragma unroll
  for (int j = 0; j < 4; ++j) hat[j] = 1.0 / (1.0 + exp(-z[j]));

  if (!side) {
#pragma unroll
    for (int j = 0; j < 4; ++j) QHAT[(t0 + tok) * 16 + k0 + j] = hat[j];
  } else {
    kh[tok][k0 + 0] = hat[0]; kh[tok][k0 + 1] = hat[1];
    kh[tok][k0 + 2] = hat[2]; kh[tok][k0 + 3] = hat[3];
    __syncthreads();
    double sk[4] = {0.0, 0.0, 0.0, 0.0};
    for (int jj = 0; jj < 16; ++jj) {
      const double kv = kh[tok][jj];
      sk[0] += Sl[(k0 + 0) * 16 + jj] * kv; sk[1] += Sl[(k0 + 1) * 16 + jj] * kv;
      sk[2] += Sl[(k0 + 2) * 16 + jj] * kv; sk[3] += Sl[(k0 + 3) * 16 + jj] * kv;
    }
#pragma unroll
    for (int j = 0; j < 4; ++j) SKT[(t0 + tok) * 16 + k0 + j] = sk[j];
  }
}

// ---------------- kSample: bits + graph + sparsity (contiguous streams) -----
__global__ __launch_bounds__(256) void kSample(
    const float* __restrict__ noise,
    const double* __restrict__ qhat, const double* __restrict__ skt,
    float* __restrict__ wsSP,
    unsigned long long* __restrict__ GB64, float* __restrict__ GOUT) {
  const int t = threadIdx.x;
  const int lane = t & 63, wave = t >> 6;
  const int nt = blockIdx.x;           // 0..31 -> n0 = nt*64
  const int mt = blockIdx.y;           // 0..3  -> m0 = mt*512
  const int bh = blockIdx.z, h = bh & 7;
  const int n0 = nt * 64;
  const int mA = mt * 512 + wave * 64 + lane;   // first m (wave-contig 64-group)
  const int mB = mA + 256;                      // second m

  // skt rows held in registers across all 64 n-rows (sequential-k order kept)
  double skvA[16], skvB[16];
  {
    const double* spA = skt + ((size_t)bh * 2048 + mA) * 16;
    const double* spB = skt + ((size_t)bh * 2048 + mB) * 16;
#pragma unroll
    for (int q = 0; q < 8; ++q) {
      *(f64x2*)(skvA + 2 * q) = *(const f64x2*)(spA + 2 * q);
      *(f64x2*)(skvB + 2 * q) = *(const f64x2*)(spB + 2 * q);
    }
  }

  const double* qbase = qhat + ((size_t)bh * 2048 + n0) * 16;   // wave-uniform
  const float* nzbase = noise + ((size_t)bh * 2048 + n0) * 2048;
  float* gobase = GOUT + ((size_t)bh * 2048 + n0) * 2048;
  unsigned long long* gbbase = GB64 + ((size_t)bh * 2048 + n0) * 32;
  const int gA = mA >> 6, gB = mB >> 6;

  int cnt = 0;
  for (int n = 0; n < 64; ++n) {
    const double* qr = qbase + (size_t)n * 16;   // uniform -> scalar loads
    double ea0 = 0.0, ea1 = 0.0;
#pragma unroll
    for (int k = 0; k < 16; ++k) {               // sequential k (validated)
      const double qk = qr[k];
      ea0 += qk * skvA[k];
      ea1 += qk * skvB[k];
    }
    const float nzA = nzbase[(size_t)n * 2048 + mA];
    const float nzB = nzbase[(size_t)n * 2048 + mB];
    const int g0 = ((double)nzA < ea0) ? 1 : 0;
    const int g1 = ((double)nzB < ea1) ? 1 : 0;
    cnt += g0 + g1;
    const unsigned long long b0 = __ballot(g0);
    const unsigned long long b1 = __ballot(g1);
    if (lane == 0) {
      gbbase[(size_t)n * 32 + gA] = b0;
      gbbase[(size_t)n * 32 + gB] = b1;
    }
    gobase[(size_t)n * 2048 + mA] = g0 ? 1.0f : 0.0f;
    gobase[(size_t)n * 2048 + mB] = g1 ? 1.0f : 0.0f;
  }
  cnt += __shfl_xor(cnt, 1); cnt += __shfl_xor(cnt, 2); cnt += __shfl_xor(cnt, 4);
  cnt += __shfl_xor(cnt, 8); cnt += __shfl_xor(cnt, 16); cnt += __shfl_xor(cnt, 32);
  if (lane == 0) atomicAdd(&wsSP[h], (float)cnt);
}

// ---------------- kCvt: K->bf16 KB, V->bf16 transposed VT ----------------
__global__ __launch_bounds__(256) void kCvt(const float* __restrict__ K,
                                            const float* __restrict__ V,
                                            unsigned short* __restrict__ KB,
                                            unsigned short* __restrict__ VT) {
  __shared__ float vt[128][65];
  const int t = threadIdx.x;
  const int bh = blockIdx.x, ch = blockIdx.y;
  const size_t base = ((size_t)bh * 2048 + ch * 128) * 64;
  for (int i = t; i < 8192; i += 256) {
    KB[base + i] = f2bf(K[base + i]);
    vt[i >> 6][i & 63] = V[base + i];
  }
  __syncthreads();
  const size_t vbase = (size_t)bh * 64 * 2048 + ch * 128;
  for (int i = t; i < 8192; i += 256) {
    const int d = i >> 7, mm = i & 127;
    VT[vbase + (size_t)d * 2048 + mm] = f2bf(vt[mm][d]);
  }
}

// ---------------- kAttn: two-phase MFMA attention (contiguous spans) --------
__global__ __launch_bounds__(256, 4) void kAttn(
    const float* __restrict__ Q, const int* __restrict__ maskp,
    const unsigned short* __restrict__ KB, const unsigned short* __restrict__ VT,
    const unsigned int* __restrict__ GB32,
    float* __restrict__ XOUT, float* __restrict__ AOUT) {
  __shared__ unsigned int bitsS[16][64];         // 4 KB
  __shared__ unsigned short stageS[4][16][32];   // 4 KB
  __shared__ float dredS[4][16];
  __shared__ float dinvS[16];
  __shared__ float xredS[16][68];                // 4.35 KB

  const int t = threadIdx.x;
  const int wave = t >> 6, lane = t & 63;
  const int bh = blockIdx.y, b = bh >> 3;
  const int n0 = blockIdx.x * 16;
  const int hi2 = lane >> 4;
  const int hi8 = hi2 << 3;
  const int g4 = hi2 << 2;
  const int lm = lane & 15;

  for (int i = t; i < 1024; i += 256)
    bitsS[i >> 6][i & 63] = GB32[((size_t)bh * 2048 + n0 + (i >> 6)) * 64 + (i & 63)];
  for (int i = t; i < 16 * 68; i += 256) ((float*)xredS)[i] = 0.f;

  // Q A-fragments (f32 -> bf16)
  const float* qrow = Q + ((size_t)bh * 2048 + n0 + lm) * 64;
  bf16x8 aq[2];
#pragma unroll
  for (int hh = 0; hh < 2; ++hh) {
    const int d0 = hi8 + hh * 32;
    const f32x4 qa = *(const f32x4*)(qrow + d0);
    const f32x4 qb = *(const f32x4*)(qrow + d0 + 4);
    bf16x8 v;
    v[0] = (__bf16)qa[0]; v[1] = (__bf16)qa[1]; v[2] = (__bf16)qa[2]; v[3] = (__bf16)qa[3];
    v[4] = (__bf16)qb[0]; v[5] = (__bf16)qb[1]; v[6] = (__bf16)qb[2]; v[7] = (__bf16)qb[3];
    aq[hh] = v;
  }

  const unsigned short* kbp = KB + (size_t)bh * 2048 * 64;
  const unsigned short* vtp = VT + (size_t)bh * 64 * 2048;
  const int* mkp = maskp + b * 2048;
  __syncthreads();

  // ======== PHASE 1: denominators (wave sweeps contiguous 512-col span) =====
  float dsum[4] = {0.f, 0.f, 0.f, 0.f};
  for (int it = 0; it < 16; ++it) {
    const int mb = (wave << 9) + (it << 5);
    f32x4 st[2];
#pragma unroll
    for (int tt = 0; tt < 2; ++tt) {
      const unsigned short* kr = kbp + (size_t)(mb + tt * 16 + lm) * 64 + hi8;
      const bf16x8 b0 = *(const bf16x8*)(kr);
      const bf16x8 b1 = *(const bf16x8*)(kr + 32);
      f32x4 acc = (f32x4){0.f, 0.f, 0.f, 0.f};
      acc = __builtin_amdgcn_mfma_f32_16x16x32_bf16(aq[0], b0, acc, 0, 0, 0);
      acc = __builtin_amdgcn_mfma_f32_16x16x32_bf16(aq[1], b1, acc, 0, 0, 0);
      st[tt] = acc;
    }
#pragma unroll
    for (int tt = 0; tt < 2; ++tt) {
      const int mv = mkp[mb + tt * 16 + lm];
      const f32x4 sv4 = st[tt];
#pragma unroll
      for (int r = 0; r < 4; ++r) {
        const int g = (bitsS[g4 + r][mb >> 5] >> (tt * 16 + lm)) & 1;
        if (g && !mv) dsum[r] += __expf(sv4[r] * 0.125f);
      }
    }
  }
#pragma unroll
  for (int r = 0; r < 4; ++r) {
    float v = dsum[r];
    v += __shfl_xor(v, 1); v += __shfl_xor(v, 2); v += __shfl_xor(v, 4); v += __shfl_xor(v, 8);
    if (lm == 0) dredS[wave][g4 + r] = v;
  }
  __syncthreads();
  if (t < 16) {
    const float dv = dredS[0][t] + dredS[1][t] + dredS[2][t] + dredS[3][t];
    dinvS[t] = 1.0f / fmaxf(dv, 1e-12f);
  }
  __syncthreads();

  // ======== PHASE 2: u rebuild, PV, attn writes ========
  const size_t rowbase = (size_t)bh * 2048 + n0;
  f32x4 xacc[4];
#pragma unroll
  for (int td = 0; td < 4; ++td) xacc[td] = (f32x4){0.f, 0.f, 0.f, 0.f};

  for (int it = 0; it < 16; ++it) {
    const int mb = (wave << 9) + (it << 5);
    f32x4 st[2];
#pragma unroll
    for (int tt = 0; tt < 2; ++tt) {
      const unsigned short* kr = kbp + (size_t)(mb + tt * 16 + lm) * 64 + hi8;
      const bf16x8 b0 = *(const bf16x8*)(kr);
      const bf16x8 b1 = *(const bf16x8*)(kr + 32);
      f32x4 acc = (f32x4){0.f, 0.f, 0.f, 0.f};
      acc = __builtin_amdgcn_mfma_f32_16x16x32_bf16(aq[0], b0, acc, 0, 0, 0);
      acc = __builtin_amdgcn_mfma_f32_16x16x32_bf16(aq[1], b1, acc, 0, 0, 0);
      st[tt] = acc;
    }
#pragma unroll
    for (int tt = 0; tt < 2; ++tt) {
      const int mv = mkp[mb + tt * 16 + lm];
      const f32x4 sv4 = st[tt];
#pragma unroll
      for (int r = 0; r < 4; ++r) {
        const int row = g4 + r;
        const int g = (bitsS[row][mb >> 5] >> (tt * 16 + lm)) & 1;
        const float u = (g && !mv) ? __expf(sv4[r] * 0.125f) : 0.f;
        const int col = tt * 16 + lm;
        stageS[wave][row][col ^ (((row >> 2) & 3) << 3)] = f2bf(u);
      }
    }
    // PV MFMA from staged A-fragments
    {
      const int rdcol = hi8 ^ (((lm >> 2) & 3) << 3);
      const bf16x8 ua = *(const bf16x8*)&stageS[wave][lm][rdcol];
#pragma unroll
      for (int td = 0; td < 4; ++td) {
        const bf16x8 vb = *(const bf16x8*)(vtp + (size_t)(td * 16 + lm) * 2048 + mb + hi8);
        xacc[td] = __builtin_amdgcn_mfma_f32_16x16x32_bf16(ua, vb, xacc[td], 0, 0, 0);
      }
    }
    // coalesced attn write for this 16x32 block (sequential across its)
    {
      const int row = lane >> 2, q = lane & 3;
      const int rc = (q * 8) ^ (((row >> 2) & 3) << 3);
      const unsigned short* up = &stageS[wave][row][rc];
      const float inv = dinvS[row];
      f32x8 av;
#pragma unroll
      for (int j = 0; j < 8; ++j) av[j] = (float)__builtin_bit_cast(__bf16, up[j]) * inv;
      *(f32x8*)(AOUT + (rowbase + row) * 2048 + mb + q * 8) = av;
    }
  }

  // ---- X cross-wave reduce + write ----
  for (int w = 0; w < 4; ++w) {
    if (wave == w) {
#pragma unroll
      for (int td = 0; td < 4; ++td)
#pragma unroll
        for (int r = 0; r < 4; ++r) xredS[g4 + r][td * 16 + lm] += xacc[td][r];
    }
    __syncthreads();
  }
  for (int i = t; i < 1024; i += 256) {
    const int nl = i >> 6, d = i & 63;
    XOUT[(rowbase + nl) * 64 + d] = xredS[nl][d] * dinvS[nl];
  }
}

// ---------------- kFin: sparsity (f32) ----------------
__global__ void kFin(const float* __restrict__ wsSP, float* __restrict__ SPOUT) {
  const int t = threadIdx.x;
  if (t < 8) SPOUT[t] = wsSP[t] * (1.0f / 8388608.0f);  // /(2*2048*2048)
}

extern "C" void kernel_launch(void* const* d_in, const int* in_sizes, int n_in,
                              void* d_out, int out_size, void* d_ws, size_t ws_size,
                              hipStream_t stream) {
  const float* Q = (const float*)d_in[0];
  const float* K = (const float*)d_in[1];
  const float* V = (const float*)d_in[2];
  const int* mask = (const int*)d_in[3];
  const float* noise = (const float*)d_in[4];
  const float* emb = (const float*)d_in[5];
  const float* W1 = (const float*)d_in[6];
  const float* b1 = (const float*)d_in[7];
  const float* W2 = (const float*)d_in[8];
  const float* b2 = (const float*)d_in[9];
  const float* W3 = (const float*)d_in[10];
  const float* b3 = (const float*)d_in[11];

  char* ws = (char*)d_ws;
  double* wsS = (double*)(ws + 0);                          // 16 KB
  float* wsSP = (float*)(ws + 16384);                       // 8 f32
  double* QHAT = (double*)(ws + 32768);                     // 4 MB f64
  double* SKT  = (double*)(ws + 32768 + 4194304);           // 4 MB f64
  // aliases (live only after kSample):
  unsigned short* KB = (unsigned short*)(ws + 32768);             // 4 MB bf16
  unsigned short* VT = (unsigned short*)(ws + 32768 + 4194304);   // 4 MB bf16
  unsigned long long* GB64 = (unsigned long long*)(ws + 32768 + 8388608);  // 8 MB
  unsigned int* GB32 = (unsigned int*)(ws + 32768 + 8388608);

  float* out = (float*)d_out;                     // FLOAT32 outputs
  float* XOUT = out;                              // 2*8*2048*64
  float* SPOUT = out + 2097152;                   // 8
  float* GOUT = out + 2097160;                    // 2*8*2048*2048
  float* AOUT = out + 69206024;                   // 2*8*2048*2048

  kS<<<8, 256, 0, stream>>>(emb, wsS, wsSP);
  kMLP<<<1024, 256, 0, stream>>>(Q, K, emb, W1, b1, W2, b2, W3, b3, wsS, QHAT, SKT);
  kSample<<<dim3(32, 4, 16), 256, 0, stream>>>(noise, QHAT, SKT, wsSP, GB64, GOUT);
  kCvt<<<dim3(16, 16), 256, 0, stream>>>(K, V, KB, VT);   // overwrites QHAT/SKT
  kAttn<<<dim3(128, 16), 256, 0, stream>>>(Q, mask, KB, VT, GB32, XOUT, AOUT);
  kFin<<<1, 64, 0, stream>>>(wsSP, SPOUT);
}